// Round 12
// baseline (1684.064 us; speedup 1.0000x reference)
//
#include <hip/hip_runtime.h>
#include <hip/hip_bf16.h>
#include <stdint.h>

#define HD   512   // hidden dim H
#define ID   128   // input dim I
#define NCLS 100   // num classes
#define TT   512   // sequence length T
#define BB   128   // batch B
#define NEMB 101   // NC + 1 embedding rows
#define THR  512   // threads per recurrence WG (8 waves, 2 waves/SIMD)

// f32 (LIVE) geometry: 32 groups x 8 WGs x 64 cols, 4 rows/group.
#define NGRPF 32
#define GWGF  8
#define RPGF  4
#define COLSF 64
// bf16 geometry (dead on this bench's f32 inputs; kept for correctness).
#define NGRPB 64
#define GWGB  4
#define RPGB  2
#define COLSB 128

#define CPAD 640   // f32 LDS C row stride (32 chunks x (16 data + 4 pad))
#define CBW  260   // packed-bf16 C row stride in u32 (256 pairs + 4 pad)
#define PSTF 5     // f32-path partials stride in float2
#define PSTB 3     // bf16-path partials stride in float2

// workspace layout (bytes)
#define WS_FLAG 0
#define WS_BAR  4096                   // u32 bars[NGRP*32] (startup barrier)
#define WS_G    65536                  // float G[101][2048]  (808 KB)
#define WS_C0   (1u * 1024 * 1024)     // C0: tagged u32 exchange buffer
#define WS_C1   (WS_C0 + 262144)
#define WS_HFB  (WS_C1 + 262144)       // float Hfb[128][512] (256 KB)
#define NBARU   4096
#define NCU     65536                  // u32s per C buffer

using bf16 = __hip_bfloat16;

__device__ __forceinline__ float b2f(bf16 v) { return __bfloat162float(v); }
__device__ __forceinline__ float sigf(float x) { return 1.0f / (1.0f + expf(-x)); }

// Agent-scope accessors — proven (die-level coherence point).
// LEDGER:
//  r1: separate flag+data exchange — 3 serial legs, lost to central RMW.
//  r3/r4: sc0 same-XCD L2 transport — sc0 loads hit stale L1. Do not retry.
//  r5: ext_vector v2f — hipcc scalarizes; packed math needs forced asm.
//  r6-r8 "nulls" VOID: flag=0 (inputs are f32); bf16-path edits were dead.
//  r9: tagged dataflow on the LIVE f32 path — WIN: 1469->1375. Barrier gone.
//  r10: wave-local early dot + narrow poll — NULL (1379).
//  r11: forced v_pk_fma_f32 (half the FMA issue) — NULL-to-slight-regress
//      (1402), VALUBusy unchanged 21.3% -> compute is PROVEN off the
//      critical chain on the live path. Step ~6700cy = ~1400 VALU + ~5200
//      wait; modeled handoff only ~2000 -> ~3000cy unexplained.
//  r12 (this round): EXCHANGE LAYOUT repack [row][col] -> [col][4 rows]
//      (word = grp*2048 + col*4 + row). A lane's 4 polled words become one
//      16B span -> 4 cldu polls hit ONE L3 line (MSHR-merged): 4x fewer
//      distinct lines per poll iteration (storm relief), and the
//      producer's 4 row-words flip in one line transition (single-observe
//      discovery). f32-exact; everything else identical to r10's scalar
//      dot. Null here => handoff is latency-intrinsic => declare ceiling.
__device__ __forceinline__ float cld(const float* p) {
    return __hip_atomic_load(p, __ATOMIC_RELAXED, __HIP_MEMORY_SCOPE_AGENT);
}
__device__ __forceinline__ void cst(float* p, float v) {
    __hip_atomic_store(p, v, __ATOMIC_RELAXED, __HIP_MEMORY_SCOPE_AGENT);
}
__device__ __forceinline__ void cstu(uint32_t* p, uint32_t v) {
    __hip_atomic_store(p, v, __ATOMIC_RELAXED, __HIP_MEMORY_SCOPE_AGENT);
}
__device__ __forceinline__ uint32_t cldu(const uint32_t* p) {
    return __hip_atomic_load(p, __ATOMIC_RELAXED, __HIP_MEMORY_SCOPE_AGENT);
}
__device__ __forceinline__ uint64_t cldu8(const uint64_t* p) {
    return __hip_atomic_load(p, __ATOMIC_RELAXED, __HIP_MEMORY_SCOPE_AGENT);
}

// pack two f32 into bf16x2 (low = first arg) — gfx950-verified instruction
__device__ __forceinline__ uint32_t pkbf(float x, float y) {
    uint32_t u;
    asm("v_cvt_pk_bf16_f32 %0, %1, %2" : "=v"(u) : "v"(x), "v"(y));
    return u;
}
// 2-way bf16 dot with f32 accumulate (VOP3P) — schedulable.
#define DOT2(acc, w, c) \
    asm("v_dot2_f32_bf16 %0, %1, %2, %0" : "+v"(acc) : "v"(w), "v"(c))

template <bool BF>
__device__ __forceinline__ float ldv(const void* p, int i) {
    if constexpr (BF) return b2f(((const bf16*)p)[i]);
    else              return ((const float*)p)[i];
}

// padded f32 Cs index for h' (16 data floats + 4 pad per chunk)
__device__ __forceinline__ int cpi(int h) { return (h >> 4) * 20 + (h & 15); }

// ---------------------------------------------------------------------------
// Group barrier — r13 flavor; STARTUP-ONLY (per-step barriers deleted).
// ---------------------------------------------------------------------------
__device__ __forceinline__ void gbarrier(unsigned* cnt, unsigned* iter, int gwg) {
    __syncthreads();
    if (threadIdx.x == 0) {
        __hip_atomic_fetch_add(cnt, 1u, __ATOMIC_RELAXED, __HIP_MEMORY_SCOPE_AGENT);
        const unsigned tgt = (*iter + 1u) * (unsigned)gwg;
        while (__hip_atomic_load(cnt, __ATOMIC_RELAXED, __HIP_MEMORY_SCOPE_AGENT) < tgt)
            ;
    }
    ++*iter;
    __syncthreads();
}

// ---------------------------------------------------------------------------
// Dtype sniffer + bars + FULL C-buffer zeroing (kills stale step-tags from
// prior graph replays — mandatory for the tagged-dataflow exchange).
// ---------------------------------------------------------------------------
__global__ void init_k(const uint32_t* __restrict__ emb_raw,
                       int* __restrict__ flag, unsigned* __restrict__ bars,
                       uint32_t* __restrict__ c0, uint32_t* __restrict__ c1) {
    const int t = blockIdx.x * 1024 + threadIdx.x;
    for (int k = t; k < NBARU; k += 8192) bars[k] = 0u;
    for (int k = t; k < NCU; k += 8192) { c0[k] = 0u; c1[k] = 0u; }
    if (t == 0) {
        uint32_t acc = 0;
        for (int i = 64; i < 128; ++i) acc |= emb_raw[i];
        *flag = (acc == 0u) ? 0 : 1;
    }
}

// ---------------------------------------------------------------------------
// G[c][j]: input-side gate pre-activations per class. j = q*512 + col,
// q in {0:f, 1:i, 2:o, 3:ctilde}; ctilde quarter pre-sigmoided.
// ---------------------------------------------------------------------------
template <bool BF>
__global__ void build_G(const int* __restrict__ flag,
                        const void* __restrict__ emb,
                        const void* __restrict__ Wfx, const void* __restrict__ Wix,
                        const void* __restrict__ Wox, const void* __restrict__ Wcx,
                        const void* __restrict__ bfv, const void* __restrict__ biv,
                        const void* __restrict__ bov, const void* __restrict__ bcv,
                        float* __restrict__ G) {
    if (*flag != (BF ? 1 : 0)) return;
    const int c   = blockIdx.x;
    const int j   = blockIdx.y * 256 + threadIdx.x;
    const int q   = j >> 9;
    const int col = j & 511;
    const void* W  = (q == 0) ? Wfx : (q == 1) ? Wix : (q == 2) ? Wox : Wcx;
    const void* bv = (q == 0) ? bfv : (q == 1) ? biv : (q == 2) ? bov : bcv;
    float acc = ldv<BF>(bv, col);
    for (int i = 0; i < ID; ++i)
        acc += ldv<BF>(emb, c * ID + i) * ldv<BF>(W, i * HD + col);
    if (q == 3) acc = sigf(acc);
    G[c * 2048 + j] = acc;
}

// ---------------------------------------------------------------------------
// Batch-split recurrence.
// BF=false (LIVE, f32): r10 structure with the exchange buffer repacked to
// [col][4 rows] interleave: word = grp*2048 + col*4 + row. Lane tid polls
// its col's 4 consecutive words (one 16B span -> one L3 line); producer
// threads (uc, ur=0..3) of one col write 4 consecutive words (one line).
// Tag protocol, dot, B1/B2, epilogue unchanged (scalar f32 dot, r10).
// BF=true: r8's tagged bf16 path (dead on this bench; own layout, gated).
// ---------------------------------------------------------------------------
template <bool BF>
__global__ __launch_bounds__(THR, 2) void recur_bs(
    const int* __restrict__ flag, const int* __restrict__ x,
    const float* __restrict__ G,
    const void* __restrict__ Wfc, const void* __restrict__ Wic,
    const void* __restrict__ Woc,
    float* __restrict__ C0, float* __restrict__ C1,
    float* __restrict__ Hfb, unsigned* __restrict__ bars)
{
    if (*flag != (BF ? 1 : 0)) return;

    __shared__ __align__(16) float Cs[RPGF * CPAD];       // 10.2 KB
    __shared__ __align__(16) uint32_t CbS[RPGB * CBW];    // 2.1 KB (bf16 path)
    __shared__ __align__(8)  float2 part2[2048 * PSTF];   // 80 KB
    __shared__ int idx[RPGF * TT];                        // 8 KB
    __shared__ int lz[RPGF];

    const int blk = blockIdx.x;
    const int tid = threadIdx.x;
    unsigned bi = 0;

    if constexpr (!BF) {
        // ===== f32 path (LIVE): wave-local tagged dataflow, packed lines ==
        const int grp   = blk >> 3;       // 0..31
        const int rank  = blk & 7;        // 0..7
        const int r0    = grp * RPGF;
        const int h0    = rank * COLSF;
        const int cp    = tid & 15;       // cols cp, +16, +32, +48
        const int chunk = tid >> 4;       // 0..31 (16 h' each)
        unsigned* bar = bars + grp * 32;  // startup barrier only

        // ---- stage x rows (2048 ints), find group start ----
        idx[tid]        = x[r0 * TT + tid];
        idx[tid + 512]  = x[r0 * TT + tid + 512];
        idx[tid + 1024] = x[r0 * TT + tid + 1024];
        idx[tid + 1536] = x[r0 * TT + tid + 1536];
        for (int k = tid; k < RPGF * CPAD; k += THR) Cs[k] = 0.0f;  // t0==TT edge
        if (tid < RPGF) lz[tid] = -1;
        __syncthreads();
        #pragma unroll
        for (int r = 0; r < RPGF; ++r)
            if (idx[r * TT + tid] == 0) atomicMax(&lz[r], tid);
        __syncthreads();
        int t0 = TT;
        #pragma unroll
        for (int r = 0; r < RPGF; ++r) t0 = min(t0, lz[r] + 1);
        // t0 is group-uniform.

        // ---- 128 pinned f32 weights: 4 cols x 2 gates x 16 h' ----
        float wf0[16], wf1[16], wf2[16], wf3[16];
        float wi0[16], wi1[16], wi2[16], wi3[16];
        #pragma unroll
        for (int k = 0; k < 16; ++k) {
            const int hp = chunk * 16 + k;
            wf0[k] = ldv<BF>(Wfc, hp * HD + h0 + cp);
            wf1[k] = ldv<BF>(Wfc, hp * HD + h0 + cp + 16);
            wf2[k] = ldv<BF>(Wfc, hp * HD + h0 + cp + 32);
            wf3[k] = ldv<BF>(Wfc, hp * HD + h0 + cp + 48);
            wi0[k] = ldv<BF>(Wic, hp * HD + h0 + cp);
            wi1[k] = ldv<BF>(Wic, hp * HD + h0 + cp + 16);
            wi2[k] = ldv<BF>(Wic, hp * HD + h0 + cp + 32);
            wi3[k] = ldv<BF>(Wic, hp * HD + h0 + cp + 48);
        }
        #pragma unroll
        for (int k = 0; k < 16; ++k)
            asm volatile("" : "+v"(wf0[k]), "+v"(wf1[k]), "+v"(wf2[k]), "+v"(wf3[k]),
                              "+v"(wi0[k]), "+v"(wi1[k]), "+v"(wi2[k]), "+v"(wi3[k]));

        const bool isUpd = (tid < COLSF * RPGF);
        const int uc = tid & 63, ur = tid >> 6;
        const int pe = cpi(tid);

        // ---- owner-init step tags (values 0), packed layout:
        // word = grp*2048 + col*4 + row. Active buf: tag t0; other buf:
        // stale marker (t0+3)&3 (can't alias the first publish t0+1). ----
        {
            uint32_t* tA = (uint32_t*)((t0 & 1) ? C1 : C0);
            uint32_t* tB = (uint32_t*)((t0 & 1) ? C0 : C1);
            if (isUpd) {
                const int w = grp * 2048 + (h0 + uc) * 4 + ur;
                cstu(tA + w, (uint32_t)(t0 & 3));
                cstu(tB + w, (uint32_t)((t0 + 3) & 3));
            }
        }
        gbarrier(bar, &bi, GWGF);         // startup only: inits visible

        float Creg = 0.0f;
        for (int t = t0; t < TT; ++t) {
            // re-pin weights every iteration (r7/r8/r10 lesson)
            #pragma unroll
            for (int k = 0; k < 16; ++k)
                asm volatile("" : "+v"(wf0[k]), "+v"(wf1[k]), "+v"(wf2[k]), "+v"(wf3[k]),
                                  "+v"(wi0[k]), "+v"(wi1[k]), "+v"(wi2[k]), "+v"(wi3[k]));

            const uint32_t* curT = (const uint32_t*)((t & 1) ? C1 : C0);
            uint32_t*       nxtT = (uint32_t*)((t & 1) ? C0 : C1);

            // ---- prefetch G gate operands (in flight during the spin) ----
            float gf = 0.f, gi = 0.f, sgc = 0.f;
            int cl = 1;
            if (isUpd) {
                cl = idx[ur * TT + t];
                const float* Gr = G + cl * 2048;
                gf  = Gr[h0 + uc];
                gi  = Gr[512 + h0 + uc];
                sgc = Gr[1536 + h0 + uc];
            }

            // ---- WAVE-LOCAL stage: lane tid polls its col's 4 consecutive
            // words (ONE 16B span -> one L3 line; all 4 tags flip in one
            // line transition). r9-style joint spin. ----
            {
                const uint32_t* s = curT + grp * 2048 + tid * 4;
                const uint32_t exp = (uint32_t)t & 3u;
                uint32_t w0, w1, w2, w3;
                for (;;) {
                    w0 = cldu(s + 0); w1 = cldu(s + 1);
                    w2 = cldu(s + 2); w3 = cldu(s + 3);
                    if ((((w0 ^ exp) | (w1 ^ exp) | (w2 ^ exp) | (w3 ^ exp)) & 3u) == 0u)
                        break;
                }
                Cs[0 * CPAD + pe] = __uint_as_float(w0 & ~3u);
                Cs[1 * CPAD + pe] = __uint_as_float(w1 & ~3u);
                Cs[2 * CPAD + pe] = __uint_as_float(w2 & ~3u);
                Cs[3 * CPAD + pe] = __uint_as_float(w3 & ~3u);
            }
            // per-wave fence: same-wave DS ops complete in order.
            asm volatile("s_waitcnt lgkmcnt(0)" ::: "memory");

            // ---- dot over own block (scalar f32, r10-proven) ----
            float f0[RPGF], f1[RPGF], f2[RPGF], f3[RPGF];
            float i0[RPGF], i1[RPGF], i2[RPGF], i3[RPGF];
            #pragma unroll
            for (int r = 0; r < RPGF; ++r) {
                f0[r] = 0.f; f1[r] = 0.f; f2[r] = 0.f; f3[r] = 0.f;
                i0[r] = 0.f; i1[r] = 0.f; i2[r] = 0.f; i3[r] = 0.f;
            }
            {
                const int cb = chunk * 5;
                #pragma unroll
                for (int j = 0; j < 4; ++j) {
                    #pragma unroll
                    for (int r = 0; r < RPGF; ++r) {
                        const float4 cv = reinterpret_cast<const float4*>(
                            Cs + r * CPAD)[cb + j];
                        f0[r] += wf0[4*j]*cv.x + wf0[4*j+1]*cv.y + wf0[4*j+2]*cv.z + wf0[4*j+3]*cv.w;
                        f1[r] += wf1[4*j]*cv.x + wf1[4*j+1]*cv.y + wf1[4*j+2]*cv.z + wf1[4*j+3]*cv.w;
                        f2[r] += wf2[4*j]*cv.x + wf2[4*j+1]*cv.y + wf2[4*j+2]*cv.z + wf2[4*j+3]*cv.w;
                        f3[r] += wf3[4*j]*cv.x + wf3[4*j+1]*cv.y + wf3[4*j+2]*cv.z + wf3[4*j+3]*cv.w;
                        i0[r] += wi0[4*j]*cv.x + wi0[4*j+1]*cv.y + wi0[4*j+2]*cv.z + wi0[4*j+3]*cv.w;
                        i1[r] += wi1[4*j]*cv.x + wi1[4*j+1]*cv.y + wi1[4*j+2]*cv.z + wi1[4*j+3]*cv.w;
                        i2[r] += wi2[4*j]*cv.x + wi2[4*j+1]*cv.y + wi2[4*j+2]*cv.z + wi2[4*j+3]*cv.w;
                        i3[r] += wi3[4*j]*cv.x + wi3[4*j+1]*cv.y + wi3[4*j+2]*cv.z + wi3[4*j+3]*cv.w;
                    }
                }
            }
            __syncthreads();              // B1: dots done; update(t-1)'s
                                          // part2 reads done
            {
                float2* p0 = part2 + (chunk * 64 + cp)      * PSTF;
                float2* p1 = part2 + (chunk * 64 + cp + 16) * PSTF;
                float2* p2 = part2 + (chunk * 64 + cp + 32) * PSTF;
                float2* p3 = part2 + (chunk * 64 + cp + 48) * PSTF;
                #pragma unroll
                for (int r = 0; r < RPGF; ++r) {
                    p0[r] = make_float2(f0[r], i0[r]);
                    p1[r] = make_float2(f1[r], i1[r]);
                    p2[r] = make_float2(f2[r], i2[r]);
                    p3[r] = make_float2(f3[r], i3[r]);
                }
            }
            __syncthreads();              // B2: partials ready

            // ---- update + tagged publish (4 row-words of a col = 1 line) --
            if (isUpd) {
                float df = 0.f, di = 0.f;
                #pragma unroll
                for (int ch = 0; ch < 32; ++ch) {
                    const float2 v = part2[(ch * 64 + uc) * PSTF + ur];
                    df += v.x;
                    di += v.y;
                }
                float Cn = sgc * sigf(gi + di) + Creg * sigf(gf + df);
                Cn = (cl > 0) ? Cn : 0.0f;
                Creg = Cn;
                cstu(nxtT + grp * 2048 + (h0 + uc) * 4 + ur,
                     (__float_as_uint(Cn) & ~3u) | ((uint32_t)(t + 1) & 3u));
            }
            // no barrier, no drain: consumers spin on the in-word tag.
        }

        // ---- o-gate + h. Cs holds the carry entering step T-1 (staged at
        // the final iteration; zeros if t0==TT). ----
        __syncthreads();                  // last update's part2 reads done
        {
            const int oc = tid & 63, och = tid >> 6;
            float ao[RPGF];
            #pragma unroll
            for (int r = 0; r < RPGF; ++r) ao[r] = 0.0f;
            #pragma unroll 4
            for (int k = 0; k < 64; ++k) {
                const int hp = och * 64 + k;
                const int hpp = cpi(hp);
                const float wo = ldv<BF>(Woc, hp * HD + h0 + oc);
                #pragma unroll
                for (int r = 0; r < RPGF; ++r)
                    ao[r] += wo * Cs[r * CPAD + hpp];
            }
            {
                float2* pp = part2 + (och * 64 + oc) * PSTF;
                #pragma unroll
                for (int r2 = 0; r2 < RPGF / 2; ++r2)
                    pp[r2] = make_float2(ao[2 * r2], ao[2 * r2 + 1]);
            }
            __syncthreads();
            if (isUpd) {
                float s = 0.f;
                #pragma unroll
                for (int ch = 0; ch < 8; ++ch) {
                    const float2 v = part2[(ch * 64 + uc) * PSTF + (ur >> 1)];
                    s += (ur & 1) ? v.y : v.x;
                }
                const int cl2 = idx[ur * TT + TT - 1];
                const float o = sigf(G[cl2 * 2048 + 1024 + h0 + uc] + s);
                Hfb[(r0 + ur) * HD + h0 + uc] = tanhf(Creg) * o;
            }
        }
    } else {
        // ===== bf16 path (dead on this bench): r8 tagged dataflow =========
        const int grp   = blk >> 2;       // 0..63
        const int rank  = blk & 3;        // 0..3
        const int r0    = grp * RPGB;
        const int h0    = rank * COLSB;
        const int cp    = tid & 31;
        const int chunk = tid >> 5;

        idx[tid]       = x[r0 * TT + tid];
        idx[tid + 512] = x[r0 * TT + tid + 512];
        for (int k = tid; k < RPGB * CBW; k += THR) CbS[k] = 0u;
        if (tid < RPGB) lz[tid] = -1;
        __syncthreads();
        #pragma unroll
        for (int r = 0; r < RPGB; ++r)
            if (idx[r * TT + tid] == 0) atomicMax(&lz[r], tid);
        __syncthreads();
        int t0 = TT;
        #pragma unroll
        for (int r = 0; r < RPGB; ++r) t0 = min(t0, lz[r] + 1);

        const uint16_t* Wfr = (const uint16_t*)Wfc;
        const uint16_t* Wir = (const uint16_t*)Wic;
        uint32_t wf0[16], wf1[16], wf2[16], wf3[16];
        uint32_t wi0[16], wi1[16], wi2[16], wi3[16];
        #pragma unroll
        for (int p = 0; p < 16; ++p) {
            const int hp = chunk * 32 + 2 * p;
            const int b0 = hp * HD + h0 + cp, b1 = (hp + 1) * HD + h0 + cp;
            wf0[p] = (uint32_t)Wfr[b0]      | ((uint32_t)Wfr[b1]      << 16);
            wf1[p] = (uint32_t)Wfr[b0 + 32] | ((uint32_t)Wfr[b1 + 32] << 16);
            wf2[p] = (uint32_t)Wfr[b0 + 64] | ((uint32_t)Wfr[b1 + 64] << 16);
            wf3[p] = (uint32_t)Wfr[b0 + 96] | ((uint32_t)Wfr[b1 + 96] << 16);
            wi0[p] = (uint32_t)Wir[b0]      | ((uint32_t)Wir[b1]      << 16);
            wi1[p] = (uint32_t)Wir[b0 + 32] | ((uint32_t)Wir[b1 + 32] << 16);
            wi2[p] = (uint32_t)Wir[b0 + 64] | ((uint32_t)Wir[b1 + 64] << 16);
            wi3[p] = (uint32_t)Wir[b0 + 96] | ((uint32_t)Wir[b1 + 96] << 16);
        }
        #pragma unroll
        for (int p = 0; p < 16; ++p)
            asm volatile("" : "+v"(wf0[p]), "+v"(wf1[p]), "+v"(wf2[p]), "+v"(wf3[p]),
                              "+v"(wi0[p]), "+v"(wi1[p]), "+v"(wi2[p]), "+v"(wi3[p]));

        const bool isUpd = (tid < COLSB * RPGB);
        const int uc = tid & 127, ur = tid >> 7;

        if (isUpd && t0 > 0) {
            uint32_t* b0 = (uint32_t*)((t0 & 1) ? C1 : C0);
            cstu(b0 + (r0 + ur) * HD + h0 + uc, (uint32_t)t0 & 0xFFFFu);
        }

        float Creg = 0.0f;
        const int srow = tid >> 8;
        const int spr  = tid & 255;

        for (int t = t0; t < TT; ++t) {
            #pragma unroll
            for (int p = 0; p < 16; ++p)
                asm volatile("" : "+v"(wf0[p]), "+v"(wf1[p]), "+v"(wf2[p]), "+v"(wf3[p]),
                                  "+v"(wi0[p]), "+v"(wi1[p]), "+v"(wi2[p]), "+v"(wi3[p]));

            const uint32_t* curT = (const uint32_t*)((t & 1) ? C1 : C0);
            uint32_t*       nxtT = (uint32_t*)((t & 1) ? C0 : C1);

            float gf = 0.f, gi = 0.f, sgc = 0.f;
            int cl = 1;
            if (isUpd) {
                cl = idx[ur * TT + t];
                const float* Gr = G + cl * 2048;
                gf  = Gr[h0 + uc];
                gi  = Gr[512 + h0 + uc];
                sgc = Gr[1536 + h0 + uc];
            }

            {
                const uint64_t* src = (const uint64_t*)(
                    curT + (r0 + srow) * HD + 2 * spr);
                const uint32_t exp = (uint32_t)t & 0xFFFFu;
                uint32_t w0, w1;
                for (;;) {
                    const uint64_t d = cldu8(src);
                    w0 = (uint32_t)d;
                    w1 = (uint32_t)(d >> 32);
                    if ((((w0 ^ exp) | (w1 ^ exp)) & 0xFFFFu) == 0u) break;
                }
                CbS[srow * CBW + spr] = (w0 >> 16) | (w1 & 0xFFFF0000u);
            }
            __syncthreads();

            float f0[RPGB], f1[RPGB], f2[RPGB], f3[RPGB];
            float i0[RPGB], i1[RPGB], i2[RPGB], i3[RPGB];
            #pragma unroll
            for (int r = 0; r < RPGB; ++r) {
                f0[r] = 0.f; f1[r] = 0.f; f2[r] = 0.f; f3[r] = 0.f;
                i0[r] = 0.f; i1[r] = 0.f; i2[r] = 0.f; i3[r] = 0.f;
            }
            {
                const int cb = chunk * 16;
                #pragma unroll
                for (int hh = 0; hh < 4; ++hh) {
                    #pragma unroll
                    for (int r = 0; r < RPGB; ++r) {
                        const uint4 cv = *reinterpret_cast<const uint4*>(
                            CbS + r * CBW + cb + 4 * hh);
                        const int p = 4 * hh;
                        DOT2(f0[r], wf0[p + 0], cv.x); DOT2(f0[r], wf0[p + 1], cv.y);
                        DOT2(f0[r], wf0[p + 2], cv.z); DOT2(f0[r], wf0[p + 3], cv.w);
                        DOT2(f1[r], wf1[p + 0], cv.x); DOT2(f1[r], wf1[p + 1], cv.y);
                        DOT2(f1[r], wf1[p + 2], cv.z); DOT2(f1[r], wf1[p + 3], cv.w);
                        DOT2(f2[r], wf2[p + 0], cv.x); DOT2(f2[r], wf2[p + 1], cv.y);
                        DOT2(f2[r], wf2[p + 2], cv.z); DOT2(f2[r], wf2[p + 3], cv.w);
                        DOT2(f3[r], wf3[p + 0], cv.x); DOT2(f3[r], wf3[p + 1], cv.y);
                        DOT2(f3[r], wf3[p + 2], cv.z); DOT2(f3[r], wf3[p + 3], cv.w);
                        DOT2(i0[r], wi0[p + 0], cv.x); DOT2(i0[r], wi0[p + 1], cv.y);
                        DOT2(i0[r], wi0[p + 2], cv.z); DOT2(i0[r], wi0[p + 3], cv.w);
                        DOT2(i1[r], wi1[p + 0], cv.x); DOT2(i1[r], wi1[p + 1], cv.y);
                        DOT2(i1[r], wi1[p + 2], cv.z); DOT2(i1[r], wi1[p + 3], cv.w);
                        DOT2(i2[r], wi2[p + 0], cv.x); DOT2(i2[r], wi2[p + 1], cv.y);
                        DOT2(i2[r], wi2[p + 2], cv.z); DOT2(i2[r], wi2[p + 3], cv.w);
                        DOT2(i3[r], wi3[p + 0], cv.x); DOT2(i3[r], wi3[p + 1], cv.y);
                        DOT2(i3[r], wi3[p + 2], cv.z); DOT2(i3[r], wi3[p + 3], cv.w);
                    }
                }
            }
            {
                float2* p0 = part2 + (chunk * 128 + cp)      * PSTB;
                float2* p1 = part2 + (chunk * 128 + cp + 32) * PSTB;
                float2* p2 = part2 + (chunk * 128 + cp + 64) * PSTB;
                float2* p3 = part2 + (chunk * 128 + cp + 96) * PSTB;
                #pragma unroll
                for (int r = 0; r < RPGB; ++r) {
                    p0[r] = make_float2(f0[r], i0[r]);
                    p1[r] = make_float2(f1[r], i1[r]);
                    p2[r] = make_float2(f2[r], i2[r]);
                    p3[r] = make_float2(f3[r], i3[r]);
                }
            }
            __syncthreads();

            if (isUpd) {
                float df = 0.f, di = 0.f;
                #pragma unroll
                for (int ch = 0; ch < 16; ++ch) {
                    const float2 v = part2[(ch * 128 + uc) * PSTB + ur];
                    df += v.x;
                    di += v.y;
                }
                float Cn = sgc * sigf(gi + di) + Creg * sigf(gf + df);
                Cn = (cl > 0) ? Cn : 0.0f;
                Creg = Cn;
                const uint32_t vb = pkbf(Cn, Cn);
                cstu(nxtT + (r0 + ur) * HD + h0 + uc,
                     (vb << 16) | ((uint32_t)(t + 1) & 0xFFFFu));
            }
        }

        __syncthreads();
        {
            const int rr = tid >> 8, wi = tid & 255;
            const uint32_t w = CbS[rr * CBW + wi];
            Cs[rr * CPAD + cpi(2 * wi)]     = __uint_as_float((w & 0xFFFFu) << 16);
            Cs[rr * CPAD + cpi(2 * wi + 1)] = __uint_as_float(w & 0xFFFF0000u);
            __syncthreads();

            const int oc = tid & 127, och = tid >> 7;
            float ao0 = 0.f, ao1 = 0.f;
            #pragma unroll 4
            for (int k = 0; k < 128; ++k) {
                const int hp  = och * 128 + k;
                const int hpp = cpi(hp);
                const float wo = ldv<BF>(Woc, hp * HD + h0 + oc);
                ao0 += wo * Cs[0 * CPAD + hpp];
                ao1 += wo * Cs[1 * CPAD + hpp];
            }
            part2[(och * 128 + oc) * PSTB] = make_float2(ao0, ao1);
            __syncthreads();
            if (isUpd) {
                float s = 0.f;
                #pragma unroll
                for (int ch = 0; ch < 4; ++ch) {
                    const float2 v = part2[(ch * 128 + uc) * PSTB];
                    s += ur ? v.y : v.x;
                }
                const int cl2 = idx[ur * TT + TT - 1];
                const float o = sigf(G[cl2 * 2048 + 1024 + h0 + uc] + s);
                Hfb[(r0 + ur) * HD + h0 + uc] = tanhf(Creg) * o;
            }
        }
    }
}

// ---------------------------------------------------------------------------
// Projection + log_softmax, one WG per batch row.
// ---------------------------------------------------------------------------
template <bool BF>
__global__ __launch_bounds__(128) void proj(
    const int* __restrict__ flag, const float* __restrict__ Hfb,
    const void* __restrict__ Wph, const void* __restrict__ bp,
    void* __restrict__ out)
{
    if (*flag != (BF ? 1 : 0)) return;
    __shared__ __align__(16) float hv[HD];
    __shared__ float p_s[NCLS];
    __shared__ float lse_s;
    const int b   = blockIdx.x;
    const int tid = threadIdx.x;

    reinterpret_cast<float4*>(hv)[tid] =
        reinterpret_cast<const float4*>(Hfb + b * HD)[tid];
    __syncthreads();

    if (tid < NCLS) {
        float p = ldv<BF>(bp, tid);
        for (int h = 0; h < HD; ++h)
            p += hv[h] * ldv<BF>(Wph, h * NCLS + tid);
        p_s[tid] = p;
    }
    __syncthreads();
    if (tid == 0) {
        float m = -1e30f;
        for (int n = 0; n < NCLS; ++n) m = fmaxf(m, p_s[n]);
        float sum = 0.0f;
        for (int n = 0; n < NCLS; ++n) sum += expf(p_s[n] - m);
        lse_s = m + logf(sum);
    }
    __syncthreads();
    if (tid < NCLS) {
        const float v = p_s[tid] - lse_s;
        if constexpr (BF) ((bf16*)out)[b * NCLS + tid] = __float2bfloat16(v);
        else              ((float*)out)[b * NCLS + tid] = v;
    }
}

// ---------------------------------------------------------------------------
extern "C" void kernel_launch(void* const* d_in, const int* in_sizes, int n_in,
                              void* d_out, int out_size, void* d_ws, size_t ws_size,
                              hipStream_t stream) {
    const int*  x   = (const int*)d_in[0];
    const void* emb = d_in[1];
    const void* Wfx = d_in[2];
    const void* Wfc = d_in[3];
    const void* bfv = d_in[4];
    const void* Wix = d_in[5];
    const void* Wic = d_in[6];
    const void* biv = d_in[7];
    const void* Wox = d_in[8];
    const void* Woc = d_in[9];
    const void* bov = d_in[10];
    const void* Wcx = d_in[11];
    const void* bcv = d_in[12];
    const void* Wph = d_in[13];
    const void* bp  = d_in[14];

    int*      flag = (int*)((char*)d_ws + WS_FLAG);
    unsigned* bars = (unsigned*)((char*)d_ws + WS_BAR);
    float*    G    = (float*)((char*)d_ws + WS_G);
    float*    C0   = (float*)((char*)d_ws + WS_C0);
    float*    C1   = (float*)((char*)d_ws + WS_C1);
    float*    Hfb  = (float*)((char*)d_ws + WS_HFB);

    init_k<<<8, 1024, 0, stream>>>((const uint32_t*)emb, flag, bars,
                                   (uint32_t*)C0, (uint32_t*)C1);

    build_G<false><<<dim3(NEMB, 8), 256, 0, stream>>>(flag, emb, Wfx, Wix, Wox, Wcx,
                                                      bfv, biv, bov, bcv, G);
    build_G<true ><<<dim3(NEMB, 8), 256, 0, stream>>>(flag, emb, Wfx, Wix, Wox, Wcx,
                                                      bfv, biv, bov, bcv, G);

    {
        // 256 blocks either way: f32 path reads blk as 32x8, bf16 as 64x4.
        void* args[] = {(void*)&flag, (void*)&x, (void*)&G,
                        (void*)&Wfc, (void*)&Wic, (void*)&Woc,
                        (void*)&C0, (void*)&C1, (void*)&Hfb, (void*)&bars};
        hipLaunchCooperativeKernel((const void*)recur_bs<false>, dim3(256), dim3(THR),
                                   args, 0, stream);
        hipLaunchCooperativeKernel((const void*)recur_bs<true>, dim3(256), dim3(THR),
                                   args, 0, stream);
    }

    proj<false><<<BB, 128, 0, stream>>>(flag, Hfb, Wph, bp, d_out);
    proj<true ><<<BB, 128, 0, stream>>>(flag, Hfb, Wph, bp, d_out);
}

// Round 13
// 1580.186 us; speedup vs baseline: 1.0657x; 1.0657x over previous
//
#include <hip/hip_runtime.h>
#include <hip/hip_bf16.h>
#include <stdint.h>

#define HD   512   // hidden dim H
#define ID   128   // input dim I
#define NCLS 100   // num classes
#define TT   512   // sequence length T
#define BB   128   // batch B
#define NEMB 101   // NC + 1 embedding rows
#define THR  512   // threads per recurrence WG (8 waves, 2 waves/SIMD)

// f32 (LIVE) geometry: 32 groups x 8 WGs x 64 cols, 4 rows/group.
#define NGRPF 32
#define GWGF  8
#define RPGF  4
#define COLSF 64
// bf16 geometry (dead on this bench's f32 inputs; kept for correctness).
#define NGRPB 64
#define GWGB  4
#define RPGB  2
#define COLSB 128

#define CPAD 640   // f32 LDS C row stride (32 chunks x (16 data + 4 pad))
#define CBW  260   // packed-bf16 C row stride in u32 (256 pairs + 4 pad)
#define PROW 2056  // f32 partials row stride in float2 (2048 slots + 8 pad)
#define PSTB 3     // bf16-path partials stride in float2

// workspace layout (bytes)
#define WS_FLAG 0
#define WS_BAR  4096                   // u32 bars[NGRP*32] (startup barrier)
#define WS_G    65536                  // float G[101][2048]  (808 KB)
#define WS_C0   (1u * 1024 * 1024)     // C0: tagged u32 exchange buffer
#define WS_C1   (WS_C0 + 262144)
#define WS_HFB  (WS_C1 + 262144)       // float Hfb[128][512] (256 KB)
#define NBARU   4096
#define NCU     65536                  // u32s per C buffer

using bf16 = __hip_bfloat16;

__device__ __forceinline__ float b2f(bf16 v) { return __bfloat162float(v); }
__device__ __forceinline__ float sigf(float x) { return 1.0f / (1.0f + expf(-x)); }

// Agent-scope accessors — proven (die-level coherence point).
// LEDGER:
//  r1: separate flag+data exchange — 3 serial legs, lost to central RMW.
//  r3/r4: sc0 same-XCD L2 transport — sc0 loads hit stale L1. Do not retry.
//  r5: ext_vector v2f — hipcc scalarizes; packed math needs forced asm.
//  r6-r8 "nulls" VOID: flag=0 (inputs are f32); bf16-path edits were dead.
//  r9: tagged dataflow on the LIVE f32 path — WIN: 1469->1375. Barrier gone.
//  r10: wave-local early dot + narrow poll — NULL (1379). Best state.
//  r11: forced v_pk_fma_f32 — NULL (1402): compute PROVEN off the chain.
//  r12: [col][4 rows] exchange repack — REGRESSION (1628): WRITE_SIZE 4x
//      (47K->189K KB). Per-wave publishes became 4B@16B-stride partial-line
//      writes -> no coalescing, L3 write churn on the polled lines. Lesson:
//      poll locality must not break PUBLISH coalescing. Do not retry.
//  r13 (this round): REVERT exchange to r10 row-major (proven) + two
//      intra-WG riders: (a) single barrier/step via part2 double-buffer
//      (write buf[t&1] -> barrier -> update reads buf[t&1]; write(t+2)
//      lands after barrier(t+1) which follows update(t)'s reads — safe);
//      (b) partials layout [row][slot] (lane-consecutive reads/writes,
//      kills the 4-way bank conflict of the (slot*5+row) layout).
__device__ __forceinline__ float cld(const float* p) {
    return __hip_atomic_load(p, __ATOMIC_RELAXED, __HIP_MEMORY_SCOPE_AGENT);
}
__device__ __forceinline__ void cst(float* p, float v) {
    __hip_atomic_store(p, v, __ATOMIC_RELAXED, __HIP_MEMORY_SCOPE_AGENT);
}
__device__ __forceinline__ void cstu(uint32_t* p, uint32_t v) {
    __hip_atomic_store(p, v, __ATOMIC_RELAXED, __HIP_MEMORY_SCOPE_AGENT);
}
__device__ __forceinline__ uint32_t cldu(const uint32_t* p) {
    return __hip_atomic_load(p, __ATOMIC_RELAXED, __HIP_MEMORY_SCOPE_AGENT);
}
__device__ __forceinline__ uint64_t cldu8(const uint64_t* p) {
    return __hip_atomic_load(p, __ATOMIC_RELAXED, __HIP_MEMORY_SCOPE_AGENT);
}

// pack two f32 into bf16x2 (low = first arg) — gfx950-verified instruction
__device__ __forceinline__ uint32_t pkbf(float x, float y) {
    uint32_t u;
    asm("v_cvt_pk_bf16_f32 %0, %1, %2" : "=v"(u) : "v"(x), "v"(y));
    return u;
}
// 2-way bf16 dot with f32 accumulate (VOP3P) — schedulable.
#define DOT2(acc, w, c) \
    asm("v_dot2_f32_bf16 %0, %1, %2, %0" : "+v"(acc) : "v"(w), "v"(c))

template <bool BF>
__device__ __forceinline__ float ldv(const void* p, int i) {
    if constexpr (BF) return b2f(((const bf16*)p)[i]);
    else              return ((const float*)p)[i];
}

// padded f32 Cs index for h' (16 data floats + 4 pad per chunk)
__device__ __forceinline__ int cpi(int h) { return (h >> 4) * 20 + (h & 15); }

// ---------------------------------------------------------------------------
// Group barrier — r13 flavor; STARTUP-ONLY (per-step barriers deleted).
// ---------------------------------------------------------------------------
__device__ __forceinline__ void gbarrier(unsigned* cnt, unsigned* iter, int gwg) {
    __syncthreads();
    if (threadIdx.x == 0) {
        __hip_atomic_fetch_add(cnt, 1u, __ATOMIC_RELAXED, __HIP_MEMORY_SCOPE_AGENT);
        const unsigned tgt = (*iter + 1u) * (unsigned)gwg;
        while (__hip_atomic_load(cnt, __ATOMIC_RELAXED, __HIP_MEMORY_SCOPE_AGENT) < tgt)
            ;
    }
    ++*iter;
    __syncthreads();
}

// ---------------------------------------------------------------------------
// Dtype sniffer + bars + FULL C-buffer zeroing (kills stale step-tags from
// prior graph replays — mandatory for the tagged-dataflow exchange).
// ---------------------------------------------------------------------------
__global__ void init_k(const uint32_t* __restrict__ emb_raw,
                       int* __restrict__ flag, unsigned* __restrict__ bars,
                       uint32_t* __restrict__ c0, uint32_t* __restrict__ c1) {
    const int t = blockIdx.x * 1024 + threadIdx.x;
    for (int k = t; k < NBARU; k += 8192) bars[k] = 0u;
    for (int k = t; k < NCU; k += 8192) { c0[k] = 0u; c1[k] = 0u; }
    if (t == 0) {
        uint32_t acc = 0;
        for (int i = 64; i < 128; ++i) acc |= emb_raw[i];
        *flag = (acc == 0u) ? 0 : 1;
    }
}

// ---------------------------------------------------------------------------
// G[c][j]: input-side gate pre-activations per class. j = q*512 + col,
// q in {0:f, 1:i, 2:o, 3:ctilde}; ctilde quarter pre-sigmoided.
// ---------------------------------------------------------------------------
template <bool BF>
__global__ void build_G(const int* __restrict__ flag,
                        const void* __restrict__ emb,
                        const void* __restrict__ Wfx, const void* __restrict__ Wix,
                        const void* __restrict__ Wox, const void* __restrict__ Wcx,
                        const void* __restrict__ bfv, const void* __restrict__ biv,
                        const void* __restrict__ bov, const void* __restrict__ bcv,
                        float* __restrict__ G) {
    if (*flag != (BF ? 1 : 0)) return;
    const int c   = blockIdx.x;
    const int j   = blockIdx.y * 256 + threadIdx.x;
    const int q   = j >> 9;
    const int col = j & 511;
    const void* W  = (q == 0) ? Wfx : (q == 1) ? Wix : (q == 2) ? Wox : Wcx;
    const void* bv = (q == 0) ? bfv : (q == 1) ? biv : (q == 2) ? bov : bcv;
    float acc = ldv<BF>(bv, col);
    for (int i = 0; i < ID; ++i)
        acc += ldv<BF>(emb, c * ID + i) * ldv<BF>(W, i * HD + col);
    if (q == 3) acc = sigf(acc);
    G[c * 2048 + j] = acc;
}

// ---------------------------------------------------------------------------
// Batch-split recurrence.
// BF=false (LIVE, f32): r10 exchange (row-major tagged words, wave-local
// narrow-poll stage, scalar f32 dot) + single barrier/step (part2 double-
// buffered, [row][slot] conflict-free layout). Per step:
//   spin own rank-block -> wave-local LDS stage -> lgkmcnt fence -> dot ->
//   write part2[t&1] -> ONE __syncthreads -> update + tagged publish.
// BF=true: r8's tagged bf16 path (dead on this bench).
// ---------------------------------------------------------------------------
template <bool BF>
__global__ __launch_bounds__(THR, 2) void recur_bs(
    const int* __restrict__ flag, const int* __restrict__ x,
    const float* __restrict__ G,
    const void* __restrict__ Wfc, const void* __restrict__ Wic,
    const void* __restrict__ Woc,
    float* __restrict__ C0, float* __restrict__ C1,
    float* __restrict__ Hfb, unsigned* __restrict__ bars)
{
    if (*flag != (BF ? 1 : 0)) return;

    __shared__ __align__(16) float Cs[RPGF * CPAD];       // 10.2 KB
    __shared__ __align__(16) uint32_t CbS[RPGB * CBW];    // 2.1 KB (bf16 path)
    __shared__ __align__(8)  float2 part2[2 * RPGF * PROW]; // 128.5 KB (2 bufs)
    __shared__ int idx[RPGF * TT];                        // 8 KB
    __shared__ int lz[RPGF];

    const int blk = blockIdx.x;
    const int tid = threadIdx.x;
    unsigned bi = 0;

    if constexpr (!BF) {
        // ===== f32 path (LIVE): wave-local tagged dataflow (r10) ==========
        const int grp   = blk >> 3;       // 0..31
        const int rank  = blk & 7;        // 0..7
        const int r0    = grp * RPGF;
        const int h0    = rank * COLSF;
        const int cp    = tid & 15;       // cols cp, +16, +32, +48
        const int chunk = tid >> 4;       // 0..31 (16 h' each)
        unsigned* bar = bars + grp * 32;  // startup barrier only

        // ---- stage x rows (2048 ints), find group start ----
        idx[tid]        = x[r0 * TT + tid];
        idx[tid + 512]  = x[r0 * TT + tid + 512];
        idx[tid + 1024] = x[r0 * TT + tid + 1024];
        idx[tid + 1536] = x[r0 * TT + tid + 1536];
        for (int k = tid; k < RPGF * CPAD; k += THR) Cs[k] = 0.0f;  // t0==TT edge
        if (tid < RPGF) lz[tid] = -1;
        __syncthreads();
        #pragma unroll
        for (int r = 0; r < RPGF; ++r)
            if (idx[r * TT + tid] == 0) atomicMax(&lz[r], tid);
        __syncthreads();
        int t0 = TT;
        #pragma unroll
        for (int r = 0; r < RPGF; ++r) t0 = min(t0, lz[r] + 1);
        // t0 is group-uniform.

        // ---- 128 pinned f32 weights: 4 cols x 2 gates x 16 h' ----
        float wf0[16], wf1[16], wf2[16], wf3[16];
        float wi0[16], wi1[16], wi2[16], wi3[16];
        #pragma unroll
        for (int k = 0; k < 16; ++k) {
            const int hp = chunk * 16 + k;
            wf0[k] = ldv<BF>(Wfc, hp * HD + h0 + cp);
            wf1[k] = ldv<BF>(Wfc, hp * HD + h0 + cp + 16);
            wf2[k] = ldv<BF>(Wfc, hp * HD + h0 + cp + 32);
            wf3[k] = ldv<BF>(Wfc, hp * HD + h0 + cp + 48);
            wi0[k] = ldv<BF>(Wic, hp * HD + h0 + cp);
            wi1[k] = ldv<BF>(Wic, hp * HD + h0 + cp + 16);
            wi2[k] = ldv<BF>(Wic, hp * HD + h0 + cp + 32);
            wi3[k] = ldv<BF>(Wic, hp * HD + h0 + cp + 48);
        }
        #pragma unroll
        for (int k = 0; k < 16; ++k)
            asm volatile("" : "+v"(wf0[k]), "+v"(wf1[k]), "+v"(wf2[k]), "+v"(wf3[k]),
                              "+v"(wi0[k]), "+v"(wi1[k]), "+v"(wi2[k]), "+v"(wi3[k]));

        const bool isUpd = (tid < COLSF * RPGF);
        const int uc = tid & 63, ur = tid >> 6;
        const int pe = cpi(tid);

        // ---- owner-init step tags (values 0), r10 row-major layout.
        // Active buf: tag t0; other buf: stale marker (t0+3)&3. ----
        {
            uint32_t* tA = (uint32_t*)((t0 & 1) ? C1 : C0);
            uint32_t* tB = (uint32_t*)((t0 & 1) ? C0 : C1);
            if (isUpd) {
                cstu(tA + (r0 + ur) * HD + h0 + uc, (uint32_t)(t0 & 3));
                cstu(tB + (r0 + ur) * HD + h0 + uc, (uint32_t)((t0 + 3) & 3));
            }
        }
        gbarrier(bar, &bi, GWGF);         // startup only: inits visible

        float Creg = 0.0f;
        for (int t = t0; t < TT; ++t) {
            // re-pin weights every iteration (r7/r8/r10 lesson)
            #pragma unroll
            for (int k = 0; k < 16; ++k)
                asm volatile("" : "+v"(wf0[k]), "+v"(wf1[k]), "+v"(wf2[k]), "+v"(wf3[k]),
                                  "+v"(wi0[k]), "+v"(wi1[k]), "+v"(wi2[k]), "+v"(wi3[k]));

            const uint32_t* curT = (const uint32_t*)((t & 1) ? C1 : C0);
            uint32_t*       nxtT = (uint32_t*)((t & 1) ? C0 : C1);

            // ---- prefetch G gate operands (in flight during the spin) ----
            float gf = 0.f, gi = 0.f, sgc = 0.f;
            int cl = 1;
            if (isUpd) {
                cl = idx[ur * TT + t];
                const float* Gr = G + cl * 2048;
                gf  = Gr[h0 + uc];
                gi  = Gr[512 + h0 + uc];
                sgc = Gr[1536 + h0 + uc];
            }

            // ---- WAVE-LOCAL stage: wave w spins only on rank-block w ----
            {
                const uint32_t* s0 = curT + (r0 + 0) * HD + tid;
                const uint32_t* s1 = curT + (r0 + 1) * HD + tid;
                const uint32_t* s2 = curT + (r0 + 2) * HD + tid;
                const uint32_t* s3 = curT + (r0 + 3) * HD + tid;
                const uint32_t exp = (uint32_t)t & 3u;
                uint32_t w0, w1, w2, w3;
                do { w0 = cldu(s0); } while ((w0 ^ exp) & 3u);
                for (;;) {
                    w1 = cldu(s1); w2 = cldu(s2); w3 = cldu(s3);
                    if ((((w1 ^ exp) | (w2 ^ exp) | (w3 ^ exp)) & 3u) == 0u)
                        break;
                }
                Cs[0 * CPAD + pe] = __uint_as_float(w0 & ~3u);
                Cs[1 * CPAD + pe] = __uint_as_float(w1 & ~3u);
                Cs[2 * CPAD + pe] = __uint_as_float(w2 & ~3u);
                Cs[3 * CPAD + pe] = __uint_as_float(w3 & ~3u);
            }
            // per-wave fence: same-wave DS ops complete in order.
            asm volatile("s_waitcnt lgkmcnt(0)" ::: "memory");

            // ---- dot over own block (scalar f32, r10-proven) ----
            float f0[RPGF], f1[RPGF], f2[RPGF], f3[RPGF];
            float i0[RPGF], i1[RPGF], i2[RPGF], i3[RPGF];
            #pragma unroll
            for (int r = 0; r < RPGF; ++r) {
                f0[r] = 0.f; f1[r] = 0.f; f2[r] = 0.f; f3[r] = 0.f;
                i0[r] = 0.f; i1[r] = 0.f; i2[r] = 0.f; i3[r] = 0.f;
            }
            {
                const int cb = chunk * 5;
                #pragma unroll
                for (int j = 0; j < 4; ++j) {
                    #pragma unroll
                    for (int r = 0; r < RPGF; ++r) {
                        const float4 cv = reinterpret_cast<const float4*>(
                            Cs + r * CPAD)[cb + j];
                        f0[r] += wf0[4*j]*cv.x + wf0[4*j+1]*cv.y + wf0[4*j+2]*cv.z + wf0[4*j+3]*cv.w;
                        f1[r] += wf1[4*j]*cv.x + wf1[4*j+1]*cv.y + wf1[4*j+2]*cv.z + wf1[4*j+3]*cv.w;
                        f2[r] += wf2[4*j]*cv.x + wf2[4*j+1]*cv.y + wf2[4*j+2]*cv.z + wf2[4*j+3]*cv.w;
                        f3[r] += wf3[4*j]*cv.x + wf3[4*j+1]*cv.y + wf3[4*j+2]*cv.z + wf3[4*j+3]*cv.w;
                        i0[r] += wi0[4*j]*cv.x + wi0[4*j+1]*cv.y + wi0[4*j+2]*cv.z + wi0[4*j+3]*cv.w;
                        i1[r] += wi1[4*j]*cv.x + wi1[4*j+1]*cv.y + wi1[4*j+2]*cv.z + wi1[4*j+3]*cv.w;
                        i2[r] += wi2[4*j]*cv.x + wi2[4*j+1]*cv.y + wi2[4*j+2]*cv.z + wi2[4*j+3]*cv.w;
                        i3[r] += wi3[4*j]*cv.x + wi3[4*j+1]*cv.y + wi3[4*j+2]*cv.z + wi3[4*j+3]*cv.w;
                    }
                }
            }

            // ---- write partials: buf[t&1], [row][slot] (lane-consecutive,
            // conflict-free). No pre-barrier needed: update(t-1) read the
            // OTHER buffer, and writes into this buffer from step t-2
            // completed before barrier(t-1) which we have all passed. ----
            {
                float2* Pb = part2 + (t & 1) * (RPGF * PROW);
                #pragma unroll
                for (int r = 0; r < RPGF; ++r) {
                    float2* Pr = Pb + r * PROW + chunk * 64;
                    Pr[cp]      = make_float2(f0[r], i0[r]);
                    Pr[cp + 16] = make_float2(f1[r], i1[r]);
                    Pr[cp + 32] = make_float2(f2[r], i2[r]);
                    Pr[cp + 48] = make_float2(f3[r], i3[r]);
                }
            }
            __syncthreads();              // SINGLE barrier: partials ready

            // ---- update + tagged publish ----
            if (isUpd) {
                const float2* Pr = part2 + (t & 1) * (RPGF * PROW) + ur * PROW;
                float df = 0.f, di = 0.f;
                #pragma unroll
                for (int ch = 0; ch < 32; ++ch) {
                    const float2 v = Pr[ch * 64 + uc];
                    df += v.x;
                    di += v.y;
                }
                float Cn = sgc * sigf(gi + di) + Creg * sigf(gf + df);
                Cn = (cl > 0) ? Cn : 0.0f;
                Creg = Cn;
                cstu(nxtT + (r0 + ur) * HD + h0 + uc,
                     (__float_as_uint(Cn) & ~3u) | ((uint32_t)(t + 1) & 3u));
            }
            // no barrier, no drain: consumers spin on the in-word tag.
        }

        // ---- o-gate + h. Cs holds the carry entering step T-1 (staged at
        // the final iteration; zeros if t0==TT). o-dot is wave-local. ----
        __syncthreads();                  // last update's part2 reads done
        {
            const int oc = tid & 63, och = tid >> 6;
            float ao[RPGF];
            #pragma unroll
            for (int r = 0; r < RPGF; ++r) ao[r] = 0.0f;
            #pragma unroll 4
            for (int k = 0; k < 64; ++k) {
                const int hp = och * 64 + k;
                const int hpp = cpi(hp);
                const float wo = ldv<BF>(Woc, hp * HD + h0 + oc);
                #pragma unroll
                for (int r = 0; r < RPGF; ++r)
                    ao[r] += wo * Cs[r * CPAD + hpp];
            }
            {
                // buf 0, rows 0..1 hold the (row-pair) o-partials
                #pragma unroll
                for (int r2 = 0; r2 < RPGF / 2; ++r2)
                    part2[r2 * PROW + och * 64 + oc] =
                        make_float2(ao[2 * r2], ao[2 * r2 + 1]);
            }
            __syncthreads();
            if (isUpd) {
                const float2* Pr = part2 + (ur >> 1) * PROW;
                float s = 0.f;
                #pragma unroll
                for (int ch = 0; ch < 8; ++ch) {
                    const float2 v = Pr[ch * 64 + uc];
                    s += (ur & 1) ? v.y : v.x;
                }
                const int cl2 = idx[ur * TT + TT - 1];
                const float o = sigf(G[cl2 * 2048 + 1024 + h0 + uc] + s);
                Hfb[(r0 + ur) * HD + h0 + uc] = tanhf(Creg) * o;
            }
        }
    } else {
        // ===== bf16 path (dead on this bench): r8 tagged dataflow =========
        const int grp   = blk >> 2;       // 0..63
        const int rank  = blk & 3;        // 0..3
        const int r0    = grp * RPGB;
        const int h0    = rank * COLSB;
        const int cp    = tid & 31;
        const int chunk = tid >> 5;

        idx[tid]       = x[r0 * TT + tid];
        idx[tid + 512] = x[r0 * TT + tid + 512];
        for (int k = tid; k < RPGB * CBW; k += THR) CbS[k] = 0u;
        if (tid < RPGB) lz[tid] = -1;
        __syncthreads();
        #pragma unroll
        for (int r = 0; r < RPGB; ++r)
            if (idx[r * TT + tid] == 0) atomicMax(&lz[r], tid);
        __syncthreads();
        int t0 = TT;
        #pragma unroll
        for (int r = 0; r < RPGB; ++r) t0 = min(t0, lz[r] + 1);

        const uint16_t* Wfr = (const uint16_t*)Wfc;
        const uint16_t* Wir = (const uint16_t*)Wic;
        uint32_t wf0[16], wf1[16], wf2[16], wf3[16];
        uint32_t wi0[16], wi1[16], wi2[16], wi3[16];
        #pragma unroll
        for (int p = 0; p < 16; ++p) {
            const int hp = chunk * 32 + 2 * p;
            const int b0 = hp * HD + h0 + cp, b1 = (hp + 1) * HD + h0 + cp;
            wf0[p] = (uint32_t)Wfr[b0]      | ((uint32_t)Wfr[b1]      << 16);
            wf1[p] = (uint32_t)Wfr[b0 + 32] | ((uint32_t)Wfr[b1 + 32] << 16);
            wf2[p] = (uint32_t)Wfr[b0 + 64] | ((uint32_t)Wfr[b1 + 64] << 16);
            wf3[p] = (uint32_t)Wfr[b0 + 96] | ((uint32_t)Wfr[b1 + 96] << 16);
            wi0[p] = (uint32_t)Wir[b0]      | ((uint32_t)Wir[b1]      << 16);
            wi1[p] = (uint32_t)Wir[b0 + 32] | ((uint32_t)Wir[b1 + 32] << 16);
            wi2[p] = (uint32_t)Wir[b0 + 64] | ((uint32_t)Wir[b1 + 64] << 16);
            wi3[p] = (uint32_t)Wir[b0 + 96] | ((uint32_t)Wir[b1 + 96] << 16);
        }
        #pragma unroll
        for (int p = 0; p < 16; ++p)
            asm volatile("" : "+v"(wf0[p]), "+v"(wf1[p]), "+v"(wf2[p]), "+v"(wf3[p]),
                              "+v"(wi0[p]), "+v"(wi1[p]), "+v"(wi2[p]), "+v"(wi3[p]));

        const bool isUpd = (tid < COLSB * RPGB);
        const int uc = tid & 127, ur = tid >> 7;

        if (isUpd && t0 > 0) {
            uint32_t* b0 = (uint32_t*)((t0 & 1) ? C1 : C0);
            cstu(b0 + (r0 + ur) * HD + h0 + uc, (uint32_t)t0 & 0xFFFFu);
        }

        float Creg = 0.0f;
        const int srow = tid >> 8;
        const int spr  = tid & 255;

        for (int t = t0; t < TT; ++t) {
            #pragma unroll
            for (int p = 0; p < 16; ++p)
                asm volatile("" : "+v"(wf0[p]), "+v"(wf1[p]), "+v"(wf2[p]), "+v"(wf3[p]),
                                  "+v"(wi0[p]), "+v"(wi1[p]), "+v"(wi2[p]), "+v"(wi3[p]));

            const uint32_t* curT = (const uint32_t*)((t & 1) ? C1 : C0);
            uint32_t*       nxtT = (uint32_t*)((t & 1) ? C0 : C1);

            float gf = 0.f, gi = 0.f, sgc = 0.f;
            int cl = 1;
            if (isUpd) {
                cl = idx[ur * TT + t];
                const float* Gr = G + cl * 2048;
                gf  = Gr[h0 + uc];
                gi  = Gr[512 + h0 + uc];
                sgc = Gr[1536 + h0 + uc];
            }

            {
                const uint64_t* src = (const uint64_t*)(
                    curT + (r0 + srow) * HD + 2 * spr);
                const uint32_t exp = (uint32_t)t & 0xFFFFu;
                uint32_t w0, w1;
                for (;;) {
                    const uint64_t d = cldu8(src);
                    w0 = (uint32_t)d;
                    w1 = (uint32_t)(d >> 32);
                    if ((((w0 ^ exp) | (w1 ^ exp)) & 0xFFFFu) == 0u) break;
                }
                CbS[srow * CBW + spr] = (w0 >> 16) | (w1 & 0xFFFF0000u);
            }
            __syncthreads();

            float f0[RPGB], f1[RPGB], f2[RPGB], f3[RPGB];
            float i0[RPGB], i1[RPGB], i2[RPGB], i3[RPGB];
            #pragma unroll
            for (int r = 0; r < RPGB; ++r) {
                f0[r] = 0.f; f1[r] = 0.f; f2[r] = 0.f; f3[r] = 0.f;
                i0[r] = 0.f; i1[r] = 0.f; i2[r] = 0.f; i3[r] = 0.f;
            }
            {
                const int cb = chunk * 16;
                #pragma unroll
                for (int hh = 0; hh < 4; ++hh) {
                    #pragma unroll
                    for (int r = 0; r < RPGB; ++r) {
                        const uint4 cv = *reinterpret_cast<const uint4*>(
                            CbS + r * CBW + cb + 4 * hh);
                        const int p = 4 * hh;
                        DOT2(f0[r], wf0[p + 0], cv.x); DOT2(f0[r], wf0[p + 1], cv.y);
                        DOT2(f0[r], wf0[p + 2], cv.z); DOT2(f0[r], wf0[p + 3], cv.w);
                        DOT2(f1[r], wf1[p + 0], cv.x); DOT2(f1[r], wf1[p + 1], cv.y);
                        DOT2(f1[r], wf1[p + 2], cv.z); DOT2(f1[r], wf1[p + 3], cv.w);
                        DOT2(f2[r], wf2[p + 0], cv.x); DOT2(f2[r], wf2[p + 1], cv.y);
                        DOT2(f2[r], wf2[p + 2], cv.z); DOT2(f2[r], wf2[p + 3], cv.w);
                        DOT2(f3[r], wf3[p + 0], cv.x); DOT2(f3[r], wf3[p + 1], cv.y);
                        DOT2(f3[r], wf3[p + 2], cv.z); DOT2(f3[r], wf3[p + 3], cv.w);
                        DOT2(i0[r], wi0[p + 0], cv.x); DOT2(i0[r], wi0[p + 1], cv.y);
                        DOT2(i0[r], wi0[p + 2], cv.z); DOT2(i0[r], wi0[p + 3], cv.w);
                        DOT2(i1[r], wi1[p + 0], cv.x); DOT2(i1[r], wi1[p + 1], cv.y);
                        DOT2(i1[r], wi1[p + 2], cv.z); DOT2(i1[r], wi1[p + 3], cv.w);
                        DOT2(i2[r], wi2[p + 0], cv.x); DOT2(i2[r], wi2[p + 1], cv.y);
                        DOT2(i2[r], wi2[p + 2], cv.z); DOT2(i2[r], wi2[p + 3], cv.w);
                        DOT2(i3[r], wi3[p + 0], cv.x); DOT2(i3[r], wi3[p + 1], cv.y);
                        DOT2(i3[r], wi3[p + 2], cv.z); DOT2(i3[r], wi3[p + 3], cv.w);
                    }
                }
            }
            {
                float2* p0 = part2 + (chunk * 128 + cp)      * PSTB;
                float2* p1 = part2 + (chunk * 128 + cp + 32) * PSTB;
                float2* p2 = part2 + (chunk * 128 + cp + 64) * PSTB;
                float2* p3 = part2 + (chunk * 128 + cp + 96) * PSTB;
                #pragma unroll
                for (int r = 0; r < RPGB; ++r) {
                    p0[r] = make_float2(f0[r], i0[r]);
                    p1[r] = make_float2(f1[r], i1[r]);
                    p2[r] = make_float2(f2[r], i2[r]);
                    p3[r] = make_float2(f3[r], i3[r]);
                }
            }
            __syncthreads();

            if (isUpd) {
                float df = 0.f, di = 0.f;
                #pragma unroll
                for (int ch = 0; ch < 16; ++ch) {
                    const float2 v = part2[(ch * 128 + uc) * PSTB + ur];
                    df += v.x;
                    di += v.y;
                }
                float Cn = sgc * sigf(gi + di) + Creg * sigf(gf + df);
                Cn = (cl > 0) ? Cn : 0.0f;
                Creg = Cn;
                const uint32_t vb = pkbf(Cn, Cn);
                cstu(nxtT + (r0 + ur) * HD + h0 + uc,
                     (vb << 16) | ((uint32_t)(t + 1) & 0xFFFFu));
            }
        }

        __syncthreads();
        {
            const int rr = tid >> 8, wi = tid & 255;
            const uint32_t w = CbS[rr * CBW + wi];
            Cs[rr * CPAD + cpi(2 * wi)]     = __uint_as_float((w & 0xFFFFu) << 16);
            Cs[rr * CPAD + cpi(2 * wi + 1)] = __uint_as_float(w & 0xFFFF0000u);
            __syncthreads();

            const int oc = tid & 127, och = tid >> 7;
            float ao0 = 0.f, ao1 = 0.f;
            #pragma unroll 4
            for (int k = 0; k < 128; ++k) {
                const int hp  = och * 128 + k;
                const int hpp = cpi(hp);
                const float wo = ldv<BF>(Woc, hp * HD + h0 + oc);
                ao0 += wo * Cs[0 * CPAD + hpp];
                ao1 += wo * Cs[1 * CPAD + hpp];
            }
            part2[(och * 128 + oc) * PSTB] = make_float2(ao0, ao1);
            __syncthreads();
            if (isUpd) {
                float s = 0.f;
                #pragma unroll
                for (int ch = 0; ch < 4; ++ch) {
                    const float2 v = part2[(ch * 128 + uc) * PSTB];
                    s += ur ? v.y : v.x;
                }
                const int cl2 = idx[ur * TT + TT - 1];
                const float o = sigf(G[cl2 * 2048 + 1024 + h0 + uc] + s);
                Hfb[(r0 + ur) * HD + h0 + uc] = tanhf(Creg) * o;
            }
        }
    }
}

// ---------------------------------------------------------------------------
// Projection + log_softmax, one WG per batch row.
// ---------------------------------------------------------------------------
template <bool BF>
__global__ __launch_bounds__(128) void proj(
    const int* __restrict__ flag, const float* __restrict__ Hfb,
    const void* __restrict__ Wph, const void* __restrict__ bp,
    void* __restrict__ out)
{
    if (*flag != (BF ? 1 : 0)) return;
    __shared__ __align__(16) float hv[HD];
    __shared__ float p_s[NCLS];
    __shared__ float lse_s;
    const int b   = blockIdx.x;
    const int tid = threadIdx.x;

    reinterpret_cast<float4*>(hv)[tid] =
        reinterpret_cast<const float4*>(Hfb + b * HD)[tid];
    __syncthreads();

    if (tid < NCLS) {
        float p = ldv<BF>(bp, tid);
        for (int h = 0; h < HD; ++h)
            p += hv[h] * ldv<BF>(Wph, h * NCLS + tid);
        p_s[tid] = p;
    }
    __syncthreads();
    if (tid == 0) {
        float m = -1e30f;
        for (int n = 0; n < NCLS; ++n) m = fmaxf(m, p_s[n]);
        float sum = 0.0f;
        for (int n = 0; n < NCLS; ++n) sum += expf(p_s[n] - m);
        lse_s = m + logf(sum);
    }
    __syncthreads();
    if (tid < NCLS) {
        const float v = p_s[tid] - lse_s;
        if constexpr (BF) ((bf16*)out)[b * NCLS + tid] = __float2bfloat16(v);
        else              ((float*)out)[b * NCLS + tid] = v;
    }
}

// ---------------------------------------------------------------------------
extern "C" void kernel_launch(void* const* d_in, const int* in_sizes, int n_in,
                              void* d_out, int out_size, void* d_ws, size_t ws_size,
                              hipStream_t stream) {
    const int*  x   = (const int*)d_in[0];
    const void* emb = d_in[1];
    const void* Wfx = d_in[2];
    const void* Wfc = d_in[3];
    const void* bfv = d_in[4];
    const void* Wix = d_in[5];
    const void* Wic = d_in[6];
    const void* biv = d_in[7];
    const void* Wox = d_in[8];
    const void* Woc = d_in[9];
    const void* bov = d_in[10];
    const void* Wcx = d_in[11];
    const void* bcv = d_in[12];
    const void* Wph = d_in[13];
    const void* bp  = d_in[14];

    int*      flag = (int*)((char*)d_ws + WS_FLAG);
    unsigned* bars = (unsigned*)((char*)d_ws + WS_BAR);
    float*    G    = (float*)((char*)d_ws + WS_G);
    float*    C0   = (float*)((char*)d_ws + WS_C0);
    float*    C1   = (float*)((char*)d_ws + WS_C1);
    float*    Hfb  = (float*)((char*)d_ws + WS_HFB);

    init_k<<<8, 1024, 0, stream>>>((const uint32_t*)emb, flag, bars,
                                   (uint32_t*)C0, (uint32_t*)C1);

    build_G<false><<<dim3(NEMB, 8), 256, 0, stream>>>(flag, emb, Wfx, Wix, Wox, Wcx,
                                                      bfv, biv, bov, bcv, G);
    build_G<true ><<<dim3(NEMB, 8), 256, 0, stream>>>(flag, emb, Wfx, Wix, Wox, Wcx,
                                                      bfv, biv, bov, bcv, G);

    {
        // 256 blocks either way: f32 path reads blk as 32x8, bf16 as 64x4.
        void* args[] = {(void*)&flag, (void*)&x, (void*)&G,
                        (void*)&Wfc, (void*)&Wic, (void*)&Woc,
                        (void*)&C0, (void*)&C1, (void*)&Hfb, (void*)&bars};
        hipLaunchCooperativeKernel((const void*)recur_bs<false>, dim3(256), dim3(THR),
                                   args, 0, stream);
        hipLaunchCooperativeKernel((const void*)recur_bs<true>, dim3(256), dim3(THR),
                                   args, 0, stream);
    }

    proj<false><<<BB, 128, 0, stream>>>(flag, Hfb, Wph, bp, d_out);
    proj<true ><<<BB, 128, 0, stream>>>(flag, Hfb, Wph, bp, d_out);
}

// Round 14
// 1419.877 us; speedup vs baseline: 1.1861x; 1.1129x over previous
//
#include <hip/hip_runtime.h>
#include <hip/hip_bf16.h>
#include <stdint.h>

#define HD   512   // hidden dim H
#define ID   128   // input dim I
#define NCLS 100   // num classes
#define TT   512   // sequence length T
#define BB   128   // batch B
#define NEMB 101   // NC + 1 embedding rows
#define THR  512   // threads per recurrence WG (8 waves, 2 waves/SIMD)

// f32 (LIVE) geometry: 32 groups x 8 WGs x 64 cols, 4 rows/group.
#define NGRPF 32
#define GWGF  8
#define RPGF  4
#define COLSF 64
// bf16 geometry (dead on this bench's f32 inputs; kept for correctness).
#define NGRPB 64
#define GWGB  4
#define RPGB  2
#define COLSB 128

#define CPAD 640   // f32 LDS C row stride (32 chunks x (16 data + 4 pad))
#define CBW  260   // packed-bf16 C row stride in u32 (256 pairs + 4 pad)
#define PROW 2056  // f32 partials row stride in float2 (2048 slots + 8 pad)
#define PSTB 3     // bf16-path partials stride in float2

// workspace layout (bytes)
#define WS_FLAG 0
#define WS_BAR  4096                   // u32 bars[NGRP*32] (startup barrier)
#define WS_G    65536                  // float G[101][2048]  (808 KB)
#define WS_C0   (1u * 1024 * 1024)     // C0: tagged u32 exchange buffer
#define WS_C1   (WS_C0 + 262144)
#define WS_HFB  (WS_C1 + 262144)       // float Hfb[128][512] (256 KB)
#define NBARU   4096
#define NCU     65536                  // u32s per C buffer

using bf16 = __hip_bfloat16;

__device__ __forceinline__ float b2f(bf16 v) { return __bfloat162float(v); }
__device__ __forceinline__ float sigf(float x) { return 1.0f / (1.0f + expf(-x)); }

// Agent-scope accessors — proven (die-level coherence point).
// LEDGER:
//  r1: separate flag+data exchange — 3 serial legs, lost to central RMW.
//  r3/r4: sc0 same-XCD L2 transport — sc0 loads hit stale L1. Do not retry.
//  r5: ext_vector v2f — hipcc scalarizes; packed math needs forced asm.
//  r6-r8 "nulls" VOID: flag=0 (inputs are f32); bf16-path edits were dead.
//  r9: tagged dataflow on the LIVE f32 path — WIN: 1469->1375. Barrier gone.
//  r10: wave-local early dot + narrow poll — NULL (1379).
//  r11: forced v_pk_fma_f32 — NULL (1402): compute PROVEN off the chain.
//  r12: [col][4 rows] exchange repack — REGRESSION (1628): WRITE_SIZE 4x.
//      Publish coalescing must not be broken for poll locality.
//  r13: revert + single barrier/step (part2 dbuf) + [row][slot] partials —
//      WIN: recur 1334 (best). But harness dur flat at 1580: ~246us of
//      non-recur overhead (7 dispatches incl. 2 cooperative, one dead).
//  r14 (this round): DISPATCH MERGE — runtime flag-branch inside single
//      kernels (build_G, recur, proj): 7 -> 4 dispatches, kills the dead
//      cooperative launch. Live f32 recurrence body byte-identical to r13.
__device__ __forceinline__ float cld(const float* p) {
    return __hip_atomic_load(p, __ATOMIC_RELAXED, __HIP_MEMORY_SCOPE_AGENT);
}
__device__ __forceinline__ void cst(float* p, float v) {
    __hip_atomic_store(p, v, __ATOMIC_RELAXED, __HIP_MEMORY_SCOPE_AGENT);
}
__device__ __forceinline__ void cstu(uint32_t* p, uint32_t v) {
    __hip_atomic_store(p, v, __ATOMIC_RELAXED, __HIP_MEMORY_SCOPE_AGENT);
}
__device__ __forceinline__ uint32_t cldu(const uint32_t* p) {
    return __hip_atomic_load(p, __ATOMIC_RELAXED, __HIP_MEMORY_SCOPE_AGENT);
}
__device__ __forceinline__ uint64_t cldu8(const uint64_t* p) {
    return __hip_atomic_load(p, __ATOMIC_RELAXED, __HIP_MEMORY_SCOPE_AGENT);
}

// pack two f32 into bf16x2 (low = first arg) — gfx950-verified instruction
__device__ __forceinline__ uint32_t pkbf(float x, float y) {
    uint32_t u;
    asm("v_cvt_pk_bf16_f32 %0, %1, %2" : "=v"(u) : "v"(x), "v"(y));
    return u;
}
// 2-way bf16 dot with f32 accumulate (VOP3P) — schedulable.
#define DOT2(acc, w, c) \
    asm("v_dot2_f32_bf16 %0, %1, %2, %0" : "+v"(acc) : "v"(w), "v"(c))

template <bool BF>
__device__ __forceinline__ float ldv(const void* p, int i) {
    if constexpr (BF) return b2f(((const bf16*)p)[i]);
    else              return ((const float*)p)[i];
}

// padded f32 Cs index for h' (16 data floats + 4 pad per chunk)
__device__ __forceinline__ int cpi(int h) { return (h >> 4) * 20 + (h & 15); }

// ---------------------------------------------------------------------------
// Group barrier — r13 flavor; STARTUP-ONLY (per-step barriers deleted).
// ---------------------------------------------------------------------------
__device__ __forceinline__ void gbarrier(unsigned* cnt, unsigned* iter, int gwg) {
    __syncthreads();
    if (threadIdx.x == 0) {
        __hip_atomic_fetch_add(cnt, 1u, __ATOMIC_RELAXED, __HIP_MEMORY_SCOPE_AGENT);
        const unsigned tgt = (*iter + 1u) * (unsigned)gwg;
        while (__hip_atomic_load(cnt, __ATOMIC_RELAXED, __HIP_MEMORY_SCOPE_AGENT) < tgt)
            ;
    }
    ++*iter;
    __syncthreads();
}

// ---------------------------------------------------------------------------
// Dtype sniffer + bars + FULL C-buffer zeroing (kills stale step-tags from
// prior graph replays — mandatory for the tagged-dataflow exchange).
// ---------------------------------------------------------------------------
__global__ void init_k(const uint32_t* __restrict__ emb_raw,
                       int* __restrict__ flag, unsigned* __restrict__ bars,
                       uint32_t* __restrict__ c0, uint32_t* __restrict__ c1) {
    const int t = blockIdx.x * 1024 + threadIdx.x;
    for (int k = t; k < NBARU; k += 8192) bars[k] = 0u;
    for (int k = t; k < NCU; k += 8192) { c0[k] = 0u; c1[k] = 0u; }
    if (t == 0) {
        uint32_t acc = 0;
        for (int i = 64; i < 128; ++i) acc |= emb_raw[i];
        *flag = (acc == 0u) ? 0 : 1;
    }
}

// ---------------------------------------------------------------------------
// G[c][j]: input-side gate pre-activations per class. j = q*512 + col,
// q in {0:f, 1:i, 2:o, 3:ctilde}; ctilde quarter pre-sigmoided.
// MERGED: one kernel, runtime dtype branch (r14).
// ---------------------------------------------------------------------------
template <bool BF>
__device__ __forceinline__ void build_G_body(
    const void* emb, const void* Wfx, const void* Wix,
    const void* Wox, const void* Wcx,
    const void* bfv, const void* biv, const void* bov, const void* bcv,
    float* G) {
    const int c   = blockIdx.x;
    const int j   = blockIdx.y * 256 + threadIdx.x;
    const int q   = j >> 9;
    const int col = j & 511;
    const void* W  = (q == 0) ? Wfx : (q == 1) ? Wix : (q == 2) ? Wox : Wcx;
    const void* bv = (q == 0) ? bfv : (q == 1) ? biv : (q == 2) ? bov : bcv;
    float acc = ldv<BF>(bv, col);
    #pragma unroll 4
    for (int i = 0; i < ID; ++i)
        acc += ldv<BF>(emb, c * ID + i) * ldv<BF>(W, i * HD + col);
    if (q == 3) acc = sigf(acc);
    G[c * 2048 + j] = acc;
}

__global__ void build_G_k(const int* __restrict__ flag,
                          const void* __restrict__ emb,
                          const void* __restrict__ Wfx, const void* __restrict__ Wix,
                          const void* __restrict__ Wox, const void* __restrict__ Wcx,
                          const void* __restrict__ bfv, const void* __restrict__ biv,
                          const void* __restrict__ bov, const void* __restrict__ bcv,
                          float* __restrict__ G) {
    if (*flag == 0) build_G_body<false>(emb, Wfx, Wix, Wox, Wcx, bfv, biv, bov, bcv, G);
    else            build_G_body<true >(emb, Wfx, Wix, Wox, Wcx, bfv, biv, bov, bcv, G);
}

// ---------------------------------------------------------------------------
// Batch-split recurrence — MERGED single cooperative kernel (r14), runtime
// dtype branch. f32 path byte-identical to r13's proven code:
//   r10 exchange (row-major tagged words, wave-local narrow-poll stage,
//   scalar f32 dot) + single barrier/step (part2 double-buffered,
//   [row][slot] conflict-free layout).
// ---------------------------------------------------------------------------
__global__ __launch_bounds__(THR, 2) void recur_bs(
    const int* __restrict__ flag, const int* __restrict__ x,
    const float* __restrict__ G,
    const void* __restrict__ Wfc, const void* __restrict__ Wic,
    const void* __restrict__ Woc,
    float* __restrict__ C0, float* __restrict__ C1,
    float* __restrict__ Hfb, unsigned* __restrict__ bars)
{
    __shared__ __align__(16) float Cs[RPGF * CPAD];       // 10.2 KB
    __shared__ __align__(16) uint32_t CbS[RPGB * CBW];    // 2.1 KB (bf16 path)
    __shared__ __align__(8)  float2 part2[2 * RPGF * PROW]; // 128.5 KB (2 bufs)
    __shared__ int idx[RPGF * TT];                        // 8 KB
    __shared__ int lz[RPGF];

    const int blk = blockIdx.x;
    const int tid = threadIdx.x;
    unsigned bi = 0;
    const int fl = *flag;

    if (fl == 0) {
        // ===== f32 path (LIVE): wave-local tagged dataflow (r13) ==========
        const int grp   = blk >> 3;       // 0..31
        const int rank  = blk & 7;        // 0..7
        const int r0    = grp * RPGF;
        const int h0    = rank * COLSF;
        const int cp    = tid & 15;       // cols cp, +16, +32, +48
        const int chunk = tid >> 4;       // 0..31 (16 h' each)
        unsigned* bar = bars + grp * 32;  // startup barrier only

        // ---- stage x rows (2048 ints), find group start ----
        idx[tid]        = x[r0 * TT + tid];
        idx[tid + 512]  = x[r0 * TT + tid + 512];
        idx[tid + 1024] = x[r0 * TT + tid + 1024];
        idx[tid + 1536] = x[r0 * TT + tid + 1536];
        for (int k = tid; k < RPGF * CPAD; k += THR) Cs[k] = 0.0f;  // t0==TT edge
        if (tid < RPGF) lz[tid] = -1;
        __syncthreads();
        #pragma unroll
        for (int r = 0; r < RPGF; ++r)
            if (idx[r * TT + tid] == 0) atomicMax(&lz[r], tid);
        __syncthreads();
        int t0 = TT;
        #pragma unroll
        for (int r = 0; r < RPGF; ++r) t0 = min(t0, lz[r] + 1);
        // t0 is group-uniform.

        // ---- 128 pinned f32 weights: 4 cols x 2 gates x 16 h' ----
        float wf0[16], wf1[16], wf2[16], wf3[16];
        float wi0[16], wi1[16], wi2[16], wi3[16];
        #pragma unroll
        for (int k = 0; k < 16; ++k) {
            const int hp = chunk * 16 + k;
            wf0[k] = ldv<false>(Wfc, hp * HD + h0 + cp);
            wf1[k] = ldv<false>(Wfc, hp * HD + h0 + cp + 16);
            wf2[k] = ldv<false>(Wfc, hp * HD + h0 + cp + 32);
            wf3[k] = ldv<false>(Wfc, hp * HD + h0 + cp + 48);
            wi0[k] = ldv<false>(Wic, hp * HD + h0 + cp);
            wi1[k] = ldv<false>(Wic, hp * HD + h0 + cp + 16);
            wi2[k] = ldv<false>(Wic, hp * HD + h0 + cp + 32);
            wi3[k] = ldv<false>(Wic, hp * HD + h0 + cp + 48);
        }
        #pragma unroll
        for (int k = 0; k < 16; ++k)
            asm volatile("" : "+v"(wf0[k]), "+v"(wf1[k]), "+v"(wf2[k]), "+v"(wf3[k]),
                              "+v"(wi0[k]), "+v"(wi1[k]), "+v"(wi2[k]), "+v"(wi3[k]));

        const bool isUpd = (tid < COLSF * RPGF);
        const int uc = tid & 63, ur = tid >> 6;
        const int pe = cpi(tid);

        // ---- owner-init step tags (values 0), r10 row-major layout.
        // Active buf: tag t0; other buf: stale marker (t0+3)&3. ----
        {
            uint32_t* tA = (uint32_t*)((t0 & 1) ? C1 : C0);
            uint32_t* tB = (uint32_t*)((t0 & 1) ? C0 : C1);
            if (isUpd) {
                cstu(tA + (r0 + ur) * HD + h0 + uc, (uint32_t)(t0 & 3));
                cstu(tB + (r0 + ur) * HD + h0 + uc, (uint32_t)((t0 + 3) & 3));
            }
        }
        gbarrier(bar, &bi, GWGF);         // startup only: inits visible

        float Creg = 0.0f;
        for (int t = t0; t < TT; ++t) {
            // re-pin weights every iteration (r7/r8/r10 lesson)
            #pragma unroll
            for (int k = 0; k < 16; ++k)
                asm volatile("" : "+v"(wf0[k]), "+v"(wf1[k]), "+v"(wf2[k]), "+v"(wf3[k]),
                                  "+v"(wi0[k]), "+v"(wi1[k]), "+v"(wi2[k]), "+v"(wi3[k]));

            const uint32_t* curT = (const uint32_t*)((t & 1) ? C1 : C0);
            uint32_t*       nxtT = (uint32_t*)((t & 1) ? C0 : C1);

            // ---- prefetch G gate operands (in flight during the spin) ----
            float gf = 0.f, gi = 0.f, sgc = 0.f;
            int cl = 1;
            if (isUpd) {
                cl = idx[ur * TT + t];
                const float* Gr = G + cl * 2048;
                gf  = Gr[h0 + uc];
                gi  = Gr[512 + h0 + uc];
                sgc = Gr[1536 + h0 + uc];
            }

            // ---- WAVE-LOCAL stage: wave w spins only on rank-block w ----
            {
                const uint32_t* s0 = curT + (r0 + 0) * HD + tid;
                const uint32_t* s1 = curT + (r0 + 1) * HD + tid;
                const uint32_t* s2 = curT + (r0 + 2) * HD + tid;
                const uint32_t* s3 = curT + (r0 + 3) * HD + tid;
                const uint32_t exp = (uint32_t)t & 3u;
                uint32_t w0, w1, w2, w3;
                do { w0 = cldu(s0); } while ((w0 ^ exp) & 3u);
                for (;;) {
                    w1 = cldu(s1); w2 = cldu(s2); w3 = cldu(s3);
                    if ((((w1 ^ exp) | (w2 ^ exp) | (w3 ^ exp)) & 3u) == 0u)
                        break;
                }
                Cs[0 * CPAD + pe] = __uint_as_float(w0 & ~3u);
                Cs[1 * CPAD + pe] = __uint_as_float(w1 & ~3u);
                Cs[2 * CPAD + pe] = __uint_as_float(w2 & ~3u);
                Cs[3 * CPAD + pe] = __uint_as_float(w3 & ~3u);
            }
            // per-wave fence: same-wave DS ops complete in order.
            asm volatile("s_waitcnt lgkmcnt(0)" ::: "memory");

            // ---- dot over own block (scalar f32, r10-proven) ----
            float f0[RPGF], f1[RPGF], f2[RPGF], f3[RPGF];
            float i0[RPGF], i1[RPGF], i2[RPGF], i3[RPGF];
            #pragma unroll
            for (int r = 0; r < RPGF; ++r) {
                f0[r] = 0.f; f1[r] = 0.f; f2[r] = 0.f; f3[r] = 0.f;
                i0[r] = 0.f; i1[r] = 0.f; i2[r] = 0.f; i3[r] = 0.f;
            }
            {
                const int cb = chunk * 5;
                #pragma unroll
                for (int j = 0; j < 4; ++j) {
                    #pragma unroll
                    for (int r = 0; r < RPGF; ++r) {
                        const float4 cv = reinterpret_cast<const float4*>(
                            Cs + r * CPAD)[cb + j];
                        f0[r] += wf0[4*j]*cv.x + wf0[4*j+1]*cv.y + wf0[4*j+2]*cv.z + wf0[4*j+3]*cv.w;
                        f1[r] += wf1[4*j]*cv.x + wf1[4*j+1]*cv.y + wf1[4*j+2]*cv.z + wf1[4*j+3]*cv.w;
                        f2[r] += wf2[4*j]*cv.x + wf2[4*j+1]*cv.y + wf2[4*j+2]*cv.z + wf2[4*j+3]*cv.w;
                        f3[r] += wf3[4*j]*cv.x + wf3[4*j+1]*cv.y + wf3[4*j+2]*cv.z + wf3[4*j+3]*cv.w;
                        i0[r] += wi0[4*j]*cv.x + wi0[4*j+1]*cv.y + wi0[4*j+2]*cv.z + wi0[4*j+3]*cv.w;
                        i1[r] += wi1[4*j]*cv.x + wi1[4*j+1]*cv.y + wi1[4*j+2]*cv.z + wi1[4*j+3]*cv.w;
                        i2[r] += wi2[4*j]*cv.x + wi2[4*j+1]*cv.y + wi2[4*j+2]*cv.z + wi2[4*j+3]*cv.w;
                        i3[r] += wi3[4*j]*cv.x + wi3[4*j+1]*cv.y + wi3[4*j+2]*cv.z + wi3[4*j+3]*cv.w;
                    }
                }
            }

            // ---- write partials: buf[t&1], [row][slot] (lane-consecutive,
            // conflict-free). No pre-barrier needed (r13 proof). ----
            {
                float2* Pb = part2 + (t & 1) * (RPGF * PROW);
                #pragma unroll
                for (int r = 0; r < RPGF; ++r) {
                    float2* Pr = Pb + r * PROW + chunk * 64;
                    Pr[cp]      = make_float2(f0[r], i0[r]);
                    Pr[cp + 16] = make_float2(f1[r], i1[r]);
                    Pr[cp + 32] = make_float2(f2[r], i2[r]);
                    Pr[cp + 48] = make_float2(f3[r], i3[r]);
                }
            }
            __syncthreads();              // SINGLE barrier: partials ready

            // ---- update + tagged publish ----
            if (isUpd) {
                const float2* Pr = part2 + (t & 1) * (RPGF * PROW) + ur * PROW;
                float df = 0.f, di = 0.f;
                #pragma unroll
                for (int ch = 0; ch < 32; ++ch) {
                    const float2 v = Pr[ch * 64 + uc];
                    df += v.x;
                    di += v.y;
                }
                float Cn = sgc * sigf(gi + di) + Creg * sigf(gf + df);
                Cn = (cl > 0) ? Cn : 0.0f;
                Creg = Cn;
                cstu(nxtT + (r0 + ur) * HD + h0 + uc,
                     (__float_as_uint(Cn) & ~3u) | ((uint32_t)(t + 1) & 3u));
            }
            // no barrier, no drain: consumers spin on the in-word tag.
        }

        // ---- o-gate + h. Cs holds the carry entering step T-1 (staged at
        // the final iteration; zeros if t0==TT). o-dot is wave-local. ----
        __syncthreads();                  // last update's part2 reads done
        {
            const int oc = tid & 63, och = tid >> 6;
            float ao[RPGF];
            #pragma unroll
            for (int r = 0; r < RPGF; ++r) ao[r] = 0.0f;
            #pragma unroll 4
            for (int k = 0; k < 64; ++k) {
                const int hp = och * 64 + k;
                const int hpp = cpi(hp);
                const float wo = ldv<false>(Woc, hp * HD + h0 + oc);
                #pragma unroll
                for (int r = 0; r < RPGF; ++r)
                    ao[r] += wo * Cs[r * CPAD + hpp];
            }
            {
                // buf 0, rows 0..1 hold the (row-pair) o-partials
                #pragma unroll
                for (int r2 = 0; r2 < RPGF / 2; ++r2)
                    part2[r2 * PROW + och * 64 + oc] =
                        make_float2(ao[2 * r2], ao[2 * r2 + 1]);
            }
            __syncthreads();
            if (isUpd) {
                const float2* Pr = part2 + (ur >> 1) * PROW;
                float s = 0.f;
                #pragma unroll
                for (int ch = 0; ch < 8; ++ch) {
                    const float2 v = Pr[ch * 64 + uc];
                    s += (ur & 1) ? v.y : v.x;
                }
                const int cl2 = idx[ur * TT + TT - 1];
                const float o = sigf(G[cl2 * 2048 + 1024 + h0 + uc] + s);
                Hfb[(r0 + ur) * HD + h0 + uc] = tanhf(Creg) * o;
            }
        }
    } else {
        // ===== bf16 path (dead on this bench): r8 tagged dataflow =========
        const int grp   = blk >> 2;       // 0..63
        const int rank  = blk & 3;        // 0..3
        const int r0    = grp * RPGB;
        const int h0    = rank * COLSB;
        const int cp    = tid & 31;
        const int chunk = tid >> 5;

        idx[tid]       = x[r0 * TT + tid];
        idx[tid + 512] = x[r0 * TT + tid + 512];
        for (int k = tid; k < RPGB * CBW; k += THR) CbS[k] = 0u;
        if (tid < RPGB) lz[tid] = -1;
        __syncthreads();
        #pragma unroll
        for (int r = 0; r < RPGB; ++r)
            if (idx[r * TT + tid] == 0) atomicMax(&lz[r], tid);
        __syncthreads();
        int t0 = TT;
        #pragma unroll
        for (int r = 0; r < RPGB; ++r) t0 = min(t0, lz[r] + 1);

        const uint16_t* Wfr = (const uint16_t*)Wfc;
        const uint16_t* Wir = (const uint16_t*)Wic;
        uint32_t wf0[16], wf1[16], wf2[16], wf3[16];
        uint32_t wi0[16], wi1[16], wi2[16], wi3[16];
        #pragma unroll
        for (int p = 0; p < 16; ++p) {
            const int hp = chunk * 32 + 2 * p;
            const int b0 = hp * HD + h0 + cp, b1 = (hp + 1) * HD + h0 + cp;
            wf0[p] = (uint32_t)Wfr[b0]      | ((uint32_t)Wfr[b1]      << 16);
            wf1[p] = (uint32_t)Wfr[b0 + 32] | ((uint32_t)Wfr[b1 + 32] << 16);
            wf2[p] = (uint32_t)Wfr[b0 + 64] | ((uint32_t)Wfr[b1 + 64] << 16);
            wf3[p] = (uint32_t)Wfr[b0 + 96] | ((uint32_t)Wfr[b1 + 96] << 16);
            wi0[p] = (uint32_t)Wir[b0]      | ((uint32_t)Wir[b1]      << 16);
            wi1[p] = (uint32_t)Wir[b0 + 32] | ((uint32_t)Wir[b1 + 32] << 16);
            wi2[p] = (uint32_t)Wir[b0 + 64] | ((uint32_t)Wir[b1 + 64] << 16);
            wi3[p] = (uint32_t)Wir[b0 + 96] | ((uint32_t)Wir[b1 + 96] << 16);
        }
        #pragma unroll
        for (int p = 0; p < 16; ++p)
            asm volatile("" : "+v"(wf0[p]), "+v"(wf1[p]), "+v"(wf2[p]), "+v"(wf3[p]),
                              "+v"(wi0[p]), "+v"(wi1[p]), "+v"(wi2[p]), "+v"(wi3[p]));

        const bool isUpd = (tid < COLSB * RPGB);
        const int uc = tid & 127, ur = tid >> 7;

        if (isUpd && t0 > 0) {
            uint32_t* b0 = (uint32_t*)((t0 & 1) ? C1 : C0);
            cstu(b0 + (r0 + ur) * HD + h0 + uc, (uint32_t)t0 & 0xFFFFu);
        }

        float Creg = 0.0f;
        const int srow = tid >> 8;
        const int spr  = tid & 255;

        for (int t = t0; t < TT; ++t) {
            #pragma unroll
            for (int p = 0; p < 16; ++p)
                asm volatile("" : "+v"(wf0[p]), "+v"(wf1[p]), "+v"(wf2[p]), "+v"(wf3[p]),
                                  "+v"(wi0[p]), "+v"(wi1[p]), "+v"(wi2[p]), "+v"(wi3[p]));

            const uint32_t* curT = (const uint32_t*)((t & 1) ? C1 : C0);
            uint32_t*       nxtT = (uint32_t*)((t & 1) ? C0 : C1);

            float gf = 0.f, gi = 0.f, sgc = 0.f;
            int cl = 1;
            if (isUpd) {
                cl = idx[ur * TT + t];
                const float* Gr = G + cl * 2048;
                gf  = Gr[h0 + uc];
                gi  = Gr[512 + h0 + uc];
                sgc = Gr[1536 + h0 + uc];
            }

            {
                const uint64_t* src = (const uint64_t*)(
                    curT + (r0 + srow) * HD + 2 * spr);
                const uint32_t exp = (uint32_t)t & 0xFFFFu;
                uint32_t w0, w1;
                for (;;) {
                    const uint64_t d = cldu8(src);
                    w0 = (uint32_t)d;
                    w1 = (uint32_t)(d >> 32);
                    if ((((w0 ^ exp) | (w1 ^ exp)) & 0xFFFFu) == 0u) break;
                }
                CbS[srow * CBW + spr] = (w0 >> 16) | (w1 & 0xFFFF0000u);
            }
            __syncthreads();

            float f0[RPGB], f1[RPGB], f2[RPGB], f3[RPGB];
            float i0[RPGB], i1[RPGB], i2[RPGB], i3[RPGB];
            #pragma unroll
            for (int r = 0; r < RPGB; ++r) {
                f0[r] = 0.f; f1[r] = 0.f; f2[r] = 0.f; f3[r] = 0.f;
                i0[r] = 0.f; i1[r] = 0.f; i2[r] = 0.f; i3[r] = 0.f;
            }
            {
                const int cb = chunk * 16;
                #pragma unroll
                for (int hh = 0; hh < 4; ++hh) {
                    #pragma unroll
                    for (int r = 0; r < RPGB; ++r) {
                        const uint4 cv = *reinterpret_cast<const uint4*>(
                            CbS + r * CBW + cb + 4 * hh);
                        const int p = 4 * hh;
                        DOT2(f0[r], wf0[p + 0], cv.x); DOT2(f0[r], wf0[p + 1], cv.y);
                        DOT2(f0[r], wf0[p + 2], cv.z); DOT2(f0[r], wf0[p + 3], cv.w);
                        DOT2(f1[r], wf1[p + 0], cv.x); DOT2(f1[r], wf1[p + 1], cv.y);
                        DOT2(f1[r], wf1[p + 2], cv.z); DOT2(f1[r], wf1[p + 3], cv.w);
                        DOT2(f2[r], wf2[p + 0], cv.x); DOT2(f2[r], wf2[p + 1], cv.y);
                        DOT2(f2[r], wf2[p + 2], cv.z); DOT2(f2[r], wf2[p + 3], cv.w);
                        DOT2(f3[r], wf3[p + 0], cv.x); DOT2(f3[r], wf3[p + 1], cv.y);
                        DOT2(f3[r], wf3[p + 2], cv.z); DOT2(f3[r], wf3[p + 3], cv.w);
                        DOT2(i0[r], wi0[p + 0], cv.x); DOT2(i0[r], wi0[p + 1], cv.y);
                        DOT2(i0[r], wi0[p + 2], cv.z); DOT2(i0[r], wi0[p + 3], cv.w);
                        DOT2(i1[r], wi1[p + 0], cv.x); DOT2(i1[r], wi1[p + 1], cv.y);
                        DOT2(i1[r], wi1[p + 2], cv.z); DOT2(i1[r], wi1[p + 3], cv.w);
                        DOT2(i2[r], wi2[p + 0], cv.x); DOT2(i2[r], wi2[p + 1], cv.y);
                        DOT2(i2[r], wi2[p + 2], cv.z); DOT2(i2[r], wi2[p + 3], cv.w);
                        DOT2(i3[r], wi3[p + 0], cv.x); DOT2(i3[r], wi3[p + 1], cv.y);
                        DOT2(i3[r], wi3[p + 2], cv.z); DOT2(i3[r], wi3[p + 3], cv.w);
                    }
                }
            }
            {
                float2* part2b = (float2*)part2;
                float2* p0 = part2b + (chunk * 128 + cp)      * PSTB;
                float2* p1 = part2b + (chunk * 128 + cp + 32) * PSTB;
                float2* p2 = part2b + (chunk * 128 + cp + 64) * PSTB;
                float2* p3 = part2b + (chunk * 128 + cp + 96) * PSTB;
                #pragma unroll
                for (int r = 0; r < RPGB; ++r) {
                    p0[r] = make_float2(f0[r], i0[r]);
                    p1[r] = make_float2(f1[r], i1[r]);
                    p2[r] = make_float2(f2[r], i2[r]);
                    p3[r] = make_float2(f3[r], i3[r]);
                }
            }
            __syncthreads();

            if (isUpd) {
                float df = 0.f, di = 0.f;
                #pragma unroll
                for (int ch = 0; ch < 16; ++ch) {
                    const float2 v = part2[(ch * 128 + uc) * PSTB + ur];
                    df += v.x;
                    di += v.y;
                }
                float Cn = sgc * sigf(gi + di) + Creg * sigf(gf + df);
                Cn = (cl > 0) ? Cn : 0.0f;
                Creg = Cn;
                const uint32_t vb = pkbf(Cn, Cn);
                cstu(nxtT + (r0 + ur) * HD + h0 + uc,
                     (vb << 16) | ((uint32_t)(t + 1) & 0xFFFFu));
            }
        }

        __syncthreads();
        {
            const int rr = tid >> 8, wi = tid & 255;
            const uint32_t w = CbS[rr * CBW + wi];
            Cs[rr * CPAD + cpi(2 * wi)]     = __uint_as_float((w & 0xFFFFu) << 16);
            Cs[rr * CPAD + cpi(2 * wi + 1)] = __uint_as_float(w & 0xFFFF0000u);
            __syncthreads();

            const int oc = tid & 127, och = tid >> 7;
            float ao0 = 0.f, ao1 = 0.f;
            #pragma unroll 4
            for (int k = 0; k < 128; ++k) {
                const int hp  = och * 128 + k;
                const int hpp = cpi(hp);
                const float wo = ldv<true>(Woc, hp * HD + h0 + oc);
                ao0 += wo * Cs[0 * CPAD + hpp];
                ao1 += wo * Cs[1 * CPAD + hpp];
            }
            part2[(och * 128 + oc) * PSTB] = make_float2(ao0, ao1);
            __syncthreads();
            if (isUpd) {
                float s = 0.f;
                #pragma unroll
                for (int ch = 0; ch < 4; ++ch) {
                    const float2 v = part2[(ch * 128 + uc) * PSTB];
                    s += ur ? v.y : v.x;
                }
                const int cl2 = idx[ur * TT + TT - 1];
                const float o = sigf(G[cl2 * 2048 + 1024 + h0 + uc] + s);
                Hfb[(r0 + ur) * HD + h0 + uc] = tanhf(Creg) * o;
            }
        }
    }
}

// ---------------------------------------------------------------------------
// Projection + log_softmax, one WG per batch row. MERGED runtime branch.
// ---------------------------------------------------------------------------
template <bool BF>
__device__ __forceinline__ void proj_body(
    const float* Hfb, const void* Wph, const void* bp, void* out,
    float* hv, float* p_s, float* lse_s) {
    const int b   = blockIdx.x;
    const int tid = threadIdx.x;

    reinterpret_cast<float4*>(hv)[tid] =
        reinterpret_cast<const float4*>(Hfb + b * HD)[tid];
    __syncthreads();

    if (tid < NCLS) {
        float p = ldv<BF>(bp, tid);
        for (int h = 0; h < HD; ++h)
            p += hv[h] * ldv<BF>(Wph, h * NCLS + tid);
        p_s[tid] = p;
    }
    __syncthreads();
    if (tid == 0) {
        float m = -1e30f;
        for (int n = 0; n < NCLS; ++n) m = fmaxf(m, p_s[n]);
        float sum = 0.0f;
        for (int n = 0; n < NCLS; ++n) sum += expf(p_s[n] - m);
        *lse_s = m + logf(sum);
    }
    __syncthreads();
    if (tid < NCLS) {
        const float v = p_s[tid] - *lse_s;
        if constexpr (BF) ((bf16*)out)[b * NCLS + tid] = __float2bfloat16(v);
        else              ((float*)out)[b * NCLS + tid] = v;
    }
}

__global__ __launch_bounds__(128) void proj_k(
    const int* __restrict__ flag, const float* __restrict__ Hfb,
    const void* __restrict__ Wph, const void* __restrict__ bp,
    void* __restrict__ out)
{
    __shared__ __align__(16) float hv[HD];
    __shared__ float p_s[NCLS];
    __shared__ float lse_s;
    if (*flag == 0) proj_body<false>(Hfb, Wph, bp, out, hv, p_s, &lse_s);
    else            proj_body<true >(Hfb, Wph, bp, out, hv, p_s, &lse_s);
}

// ---------------------------------------------------------------------------
extern "C" void kernel_launch(void* const* d_in, const int* in_sizes, int n_in,
                              void* d_out, int out_size, void* d_ws, size_t ws_size,
                              hipStream_t stream) {
    const int*  x   = (const int*)d_in[0];
    const void* emb = d_in[1];
    const void* Wfx = d_in[2];
    const void* Wfc = d_in[3];
    const void* bfv = d_in[4];
    const void* Wix = d_in[5];
    const void* Wic = d_in[6];
    const void* biv = d_in[7];
    const void* Wox = d_in[8];
    const void* Woc = d_in[9];
    const void* bov = d_in[10];
    const void* Wcx = d_in[11];
    const void* bcv = d_in[12];
    const void* Wph = d_in[13];
    const void* bp  = d_in[14];

    int*      flag = (int*)((char*)d_ws + WS_FLAG);
    unsigned* bars = (unsigned*)((char*)d_ws + WS_BAR);
    float*    G    = (float*)((char*)d_ws + WS_G);
    float*    C0   = (float*)((char*)d_ws + WS_C0);
    float*    C1   = (float*)((char*)d_ws + WS_C1);
    float*    Hfb  = (float*)((char*)d_ws + WS_HFB);

    init_k<<<8, 1024, 0, stream>>>((const uint32_t*)emb, flag, bars,
                                   (uint32_t*)C0, (uint32_t*)C1);

    build_G_k<<<dim3(NEMB, 8), 256, 0, stream>>>(flag, emb, Wfx, Wix, Wox, Wcx,
                                                 bfv, biv, bov, bcv, G);

    {
        // 256 blocks: f32 path reads blk as 32x8, bf16 as 64x4 (runtime).
        void* args[] = {(void*)&flag, (void*)&x, (void*)&G,
                        (void*)&Wfc, (void*)&Wic, (void*)&Woc,
                        (void*)&C0, (void*)&C1, (void*)&Hfb, (void*)&bars};
        hipLaunchCooperativeKernel((const void*)recur_bs, dim3(256), dim3(THR),
                                   args, 0, stream);
    }

    proj_k<<<BB, 128, 0, stream>>>(flag, Hfb, Wph, bp, d_out);
}